// Round 11
// baseline (648.726 us; speedup 1.0000x reference)
//
#include <hip/hip_runtime.h>

#define NPTS 60000
#define C 128
#define K 32
#define FF 512
#define CO 128
#define H 8
#define DH 16
#define EPS 1e-5f

// ---- fp32 weight layout (float elements) ----
constexpr int OFF_INPROJ_W = 0;          // 384*128
constexpr int OFF_INPROJ_B = 49152;      // 384
constexpr int OFF_OUT_W    = 49536;      // 16384
constexpr int OFF_OUT_B    = 65920;      // 128
constexpr int OFF_QPOS_W   = 66048;      // 384
constexpr int OFF_QPOS_B   = 66432;      // 128
constexpr int OFF_KPOS_W   = 66560;      // 384
constexpr int OFF_KPOS_B   = 66944;      // 128
constexpr int OFF_N1G      = 67072;
constexpr int OFF_N1B      = 67200;
constexpr int OFF_N2G      = 67328;
constexpr int OFF_N2B      = 67456;
constexpr int OFF_LIN1_W   = 67584;      // 65536
constexpr int OFF_LIN1_B   = 133120;     // 512
constexpr int OFF_LIN2_W   = 133632;     // 65536
constexpr int OFF_LIN2_B   = 199168;     // 128
constexpr int OFF_OUTL_W   = 199296;     // 16384
constexpr int OFF_OUTL_B   = 215680;     // 128
constexpr int OFF_BOG      = 215808;
constexpr int OFF_BOB      = 215936;
constexpr int WTOTAL       = 216064;

// ---- bf16 weight copies (ushort elements within wsB) ----
constexpr int B_INPROJ = 0;        // 384x128
constexpr int B_OUTW   = 49152;    // 128x128 (layout keep)
constexpr int B_LIN1   = 65536;    // 512x128
constexpr int B_LIN2   = 131072;   // 128x512
constexpr int B_OUTL   = 196608;   // 128x128
constexpr int B_WKT    = 212992;   // 128x128
constexpr int B_KPW4   = 229376;   // 128 x float4 (fp32, 2048 B)
constexpr int B_M      = 230400;   // 128x1024 bf16, FRAGMENT-ORDER (see k_mkmat)
constexpr int B_OB2    = 361472;   // 128 fp32: out_b + outw@bv
constexpr size_t OFF_WB_BYTES  = 1587456;
constexpr size_t OFF_BIG_BYTES = 2310912;
constexpr size_t QK_BYTES = (size_t)NPTS * 1024 * 2;   // qkt rows; reused as z rows

typedef __attribute__((ext_vector_type(8))) short bfrag8;
typedef __attribute__((ext_vector_type(4))) float f32x4;

__device__ __forceinline__ float bf2f(unsigned short s) {
    return __uint_as_float(((unsigned)s) << 16);
}
__device__ __forceinline__ unsigned short f2bf(float f) {
    unsigned u = __float_as_uint(f);
    u += 0x7fffu + ((u >> 16) & 1u);
    return (unsigned short)(u >> 16);
}
__device__ __forceinline__ float ldE(const float* p, long i) { return p[i]; }
__device__ __forceinline__ float ldE(const unsigned short* p, long i) { return bf2f(p[i]); }
__device__ __forceinline__ void stE(float* p, long i, float v) { p[i] = v; }
__device__ __forceinline__ void stE(unsigned short* p, long i, float v) { p[i] = f2bf(v); }
__device__ __forceinline__ float ldF(const void* p, long i, int bf) {
    return bf ? bf2f(((const unsigned short*)p)[i]) : ((const float*)p)[i];
}
__device__ __forceinline__ bfrag8 ldfrag(const unsigned short* base, int stride, int lane, int k0) {
    return *(const bfrag8*)(base + (lane & 15) * stride + k0 + ((lane >> 4) << 3));
}
__device__ __forceinline__ unsigned cvtpk(float lo, float hi) {
    unsigned r;
    asm("v_cvt_pk_bf16_f32 %0, %1, %2" : "=v"(r) : "v"(lo), "v"(hi));
    return r;
}

// ---- dtype probe ----
__global__ __launch_bounds__(256) void k_detect(const unsigned short* __restrict__ f,
                                                int* __restrict__ flag) {
    __shared__ int cnt_s;
    if (threadIdx.x == 0) cnt_s = 0;
    __syncthreads();
    int sane = 0;
    for (int j = 0; j < 16; ++j) {
        unsigned short u = f[threadIdx.x * 16 + j];
        int e = (u >> 7) & 255;
        sane += (u == 0 || (e >= 100 && e <= 142)) ? 1 : 0;
    }
    atomicAdd(&cnt_s, sane);
    __syncthreads();
    if (threadIdx.x == 0) *flag = (cnt_s >= 3686) ? 1 : 0;
}

struct WTab {
    const void* src[20];
    int beg[20];
    int end[20];
    int bo[20];
};

__global__ __launch_bounds__(256) void k_cvt_weights(WTab tab, float* __restrict__ ws,
                                                     unsigned short* __restrict__ wsB,
                                                     const int* __restrict__ flagp) {
    int bf = *flagp;
    int gid = blockIdx.x * 256 + threadIdx.x;
    #pragma unroll
    for (int j = 0; j < 20; ++j) {
        if (gid >= tab.beg[j] && gid < tab.end[j]) {
            int off = gid - tab.beg[j];
            float v;
            unsigned short raw;
            if (bf) { raw = ((const unsigned short*)tab.src[j])[off]; v = bf2f(raw); }
            else    { v = ((const float*)tab.src[j])[off]; raw = f2bf(v); }
            ws[gid] = v;
            if (tab.bo[j] >= 0) wsB[tab.bo[j] + off] = raw;
            if (j == 0 && off >= 16384 && off < 32768) {
                int r = (off >> 7) - 128;
                int c = off & 127;
                wsB[B_WKT + c * C + r] = raw;
            }
            if (j == 6) {
                int c = off / 3, comp = off - 3 * c;
                ((float*)(wsB + B_KPW4))[c * 4 + comp] = v;
            }
            if (j == 7) {
                ((float*)(wsB + B_KPW4))[off * 4 + 3] = v;
            }
        }
    }
}

// ---- precompute M in MFMA-fragment order ; ob2 ----
// M2 layout: for n-tile g=n>>4, k-chunk c=k>>5: element M[n][k] lives at
//   (g*32+c)*512 + lane*8 + (k&7),  lane = ((k&31)>>3)*16 + (n&15)
// so a wave's b-fragment load for (g,c) is ONE contiguous 1KB block.
__global__ __launch_bounds__(256) void k_mkmat(const float* __restrict__ wsW,
                                               unsigned short* __restrict__ wsBmut) {
    int j = blockIdx.x;   // output col n
    int t = threadIdx.x;
    const float* outw = wsW + OFF_OUT_W + j * C;
    #pragma unroll
    for (int i = 0; i < 4; ++i) {
        int idx = t + i * 256;        // k in 0..1023
        int h = idx >> 7, cp = idx & 127;
        float s = 0.f;
        const float* wvh = wsW + OFF_INPROJ_W + (256 + h * 16) * C + cp;
        const float* owh = outw + h * 16;
        #pragma unroll
        for (int d = 0; d < 16; ++d)
            s += owh[d] * wvh[d * C];
        int g = j >> 4, c = idx >> 5, r = idx & 31;
        int lane = ((r >> 3) << 4) + (j & 15);
        wsBmut[B_M + (g * 32 + c) * 512 + lane * 8 + (r & 7)] = f2bf(s);
    }
    if (t == 0) {
        float s = wsW[OFF_OUT_B + j];
        const float* bv = wsW + OFF_INPROJ_B + 256;
        for (int c = 0; c < C; ++c) s += outw[c] * bv[c];
        ((float*)(wsBmut + B_OB2))[j] = s;
    }
}

// ---- fused coords + qpos + Q projection + per-head qkt precompute ----
__global__ __launch_bounds__(256) void k_proj(
    const float* __restrict__ wsW, const unsigned short* __restrict__ wsB,
    const void* __restrict__ featv, const int* __restrict__ flagp,
    const int* __restrict__ indices, float* __restrict__ coords,
    unsigned short* __restrict__ Qk)
{
    __shared__ __align__(16) unsigned short sqb[32][136];
    __shared__ __align__(16) unsigned short sqh[32][136];
    __shared__ __align__(16) unsigned short sqk[2][32][136];
    __shared__ float scd[32][4];
    int t = threadIdx.x;
    int row0 = blockIdx.x * 32;
    const int bf = *flagp;
    if (t < 96) {
        int r = t / 3, j = t - 3 * r;
        int n = row0 + r;
        int srci = (j == 0) ? 3 : (j == 1 ? 2 : 1);
        float vs = (j == 2) ? 0.2f : 0.1f;
        float mn = (j == 2) ? -3.0f : -40.0f;
        float v = ((float)indices[n * 4 + srci] + 0.5f) * vs + mn;
        scd[r][j] = v;
        coords[n * 3 + j] = v;
    }
    __syncthreads();
    const float* qpw = wsW + OFF_QPOS_W;
    const float* qpb = wsW + OFF_QPOS_B;
    for (int i = t; i < 32 * C; i += 256) {
        int r = i >> 7, c = i & 127;
        float x = ldF(featv, (long)row0 * C + i, bf);
        float a = qpb[c] + scd[r][0]*qpw[c*3] + scd[r][1]*qpw[c*3+1] + scd[r][2]*qpw[c*3+2];
        sqb[r][c] = f2bf(x + fmaxf(a, 0.0f));
    }
    __syncthreads();
    int lane = t & 63, w = t >> 6;
    int col = lane & 15, quad = lane >> 4;
    for (int tid = w; tid < 16; tid += 4) {
        int mt = tid & 1, nt = tid >> 1, n0 = nt * 16;
        f32x4 acc = {0.f, 0.f, 0.f, 0.f};
        const unsigned short* aB = &sqb[mt*16][0];
        const unsigned short* bB = wsB + B_INPROJ + n0 * C;
        #pragma unroll
        for (int kt = 0; kt < 4; ++kt) {
            bfrag8 a = ldfrag(aB, 136, lane, kt*32);
            bfrag8 b = ldfrag(bB, C, lane, kt*32);
            acc = __builtin_amdgcn_mfma_f32_16x16x32_bf16(a, b, acc, 0, 0, 0);
        }
        #pragma unroll
        for (int r = 0; r < 4; ++r) {
            int n = n0 + col;
            sqh[mt*16 + quad*4 + r][n] = f2bf(acc[r] + wsW[OFF_INPROJ_B + n]);
        }
    }
    __syncthreads();
    const unsigned short* wkT = wsB + B_WKT;
    bfrag8 zf = {0,0,0,0,0,0,0,0};
    for (int h = 0; h < 8; ++h) {
        for (int tid = w; tid < 16; tid += 4) {
            int mt = tid & 1, nt = tid >> 1, n0 = nt * 16;
            bfrag8 a = zf, b = zf;
            if (quad < 2) {
                a = *(const bfrag8*)(&sqh[mt*16 + col][h*16 + quad*8]);
                b = *(const bfrag8*)(wkT + (n0 + col) * C + h*16 + quad*8);
            }
            f32x4 acc = {0.f, 0.f, 0.f, 0.f};
            acc = __builtin_amdgcn_mfma_f32_16x16x32_bf16(a, b, acc, 0, 0, 0);
            #pragma unroll
            for (int r = 0; r < 4; ++r)
                sqk[h & 1][mt*16 + quad*4 + r][n0 + col] = f2bf(acc[r]);
        }
        __syncthreads();
        for (int i = t; i < 2048; i += 256) {
            int r = i >> 6, cp = i & 63;
            unsigned v = *(const unsigned*)&sqk[h & 1][r][2 * cp];
            ((unsigned*)Qk)[(long)(row0 + r) * 512 + h * 64 + cp] = v;
        }
    }
}

// ---- attention: TWO waves per block (1 point), same 10.5 KB LDS ----
// R9 counters: 1-wave/block capped occupancy at 38% (LDS-limited 15 blk/CU),
// HBM at 46%. 2 waves share one point's LDS -> 30 waves/CU. Phases split:
// gather 16 keys/wave, QK nt=wv, softmax h=t>>4 (16-lane groups), PV nt=wv*4+i
// (wave0 writes z cols 0-63 while wave1 reads cols 64-127: disjoint).
__global__ __launch_bounds__(128, 8) void k_attn(
    const float* __restrict__ wsW, const unsigned short* __restrict__ wsB,
    const float* __restrict__ coords, const int* __restrict__ key_idx,
    const void* __restrict__ featv, const int* __restrict__ flagp,
    unsigned short* __restrict__ Qk)
{
    __shared__ __align__(16) unsigned short P[32][136];
    __shared__ __align__(16) float SC[8][36];
    __shared__ __align__(16) float REL[32][4];
    __shared__ __align__(16) int   GS[32];

    int t = threadIdx.x;
    int l = t & 63;
    int wv = t >> 6;
    int n = blockIdx.x;
    int col = l & 15, quad = l >> 4;
    int c0 = 2 * l;
    const int bf = *flagp;

    const float* kpwp = wsW + OFF_KPOS_W;
    float kw00 = kpwp[c0*3],   kw01 = kpwp[c0*3+1], kw02 = kpwp[c0*3+2];
    float kw10 = kpwp[c0*3+3], kw11 = kpwp[c0*3+4], kw12 = kpwp[c0*3+5];
    float kb0 = wsW[OFF_KPOS_B + c0], kb1 = wsW[OFF_KPOS_B + c0 + 1];

    if (t < 32) GS[t] = key_idx[n * K + t];
    bfrag8 ak[4];
    {
        const unsigned short* qkrow = Qk + (long)n * 1024 + (col & 7) * 128;
        #pragma unroll
        for (int ks = 0; ks < 4; ++ks)
            ak[ks] = *(const bfrag8*)(qkrow + ks * 32 + quad * 8);
    }
    if (t < 32) {
        float cenx = coords[n*3+0], ceny = coords[n*3+1], cenz = coords[n*3+2];
        int gc = max(GS[t], 0);
        REL[t][0] = coords[gc*3+0] - cenx;
        REL[t][1] = coords[gc*3+1] - ceny;
        REL[t][2] = coords[gc*3+2] - cenz;
        REL[t][3] = 0.f;
    }
    __syncthreads();

    int k0w = wv * 16;   // this wave's 16 keys
    if (bf) {
        const unsigned* xb = (const unsigned*)featv;
        unsigned xv[16];
        #pragma unroll
        for (int j = 0; j < 16; ++j) {
            int gcs = __builtin_amdgcn_readfirstlane(max(GS[k0w + j], 0));
            xv[j] = xb[(long)gcs * 64 + l];
        }
        #pragma unroll
        for (int j = 0; j < 16; ++j) {
            int k = k0w + j;
            float4 rr = *(const float4*)&REL[k][0];
            float p0 = bf2f((unsigned short)xv[j])
                     + fmaxf(kb0 + rr.x*kw00 + rr.y*kw01 + rr.z*kw02, 0.f);
            float p1 = bf2f((unsigned short)(xv[j] >> 16))
                     + fmaxf(kb1 + rr.x*kw10 + rr.y*kw11 + rr.z*kw12, 0.f);
            *(unsigned*)&P[k][c0] = cvtpk(p0, p1);
        }
    } else {
        const float2* xf = (const float2*)featv;
        #pragma unroll
        for (int kc = 0; kc < 16; kc += 8) {
            float2 xv[8];
            #pragma unroll
            for (int j = 0; j < 8; ++j) {
                int gcs = __builtin_amdgcn_readfirstlane(max(GS[k0w + kc + j], 0));
                xv[j] = xf[(long)gcs * 64 + l];
            }
            #pragma unroll
            for (int j = 0; j < 8; ++j) {
                int k = k0w + kc + j;
                float4 rr = *(const float4*)&REL[k][0];
                float p0 = xv[j].x + fmaxf(kb0 + rr.x*kw00 + rr.y*kw01 + rr.z*kw02, 0.f);
                float p1 = xv[j].y + fmaxf(kb1 + rr.x*kw10 + rr.y*kw11 + rr.z*kw12, 0.f);
                *(unsigned*)&P[k][c0] = cvtpk(p0, p1);
            }
        }
    }
    __syncthreads();

    // QK: wave wv handles column stripe nt = wv
    {
        int nt = wv;
        int g = GS[nt * 16 + col];
        f32x4 acc = {0.f, 0.f, 0.f, 0.f};
        #pragma unroll
        for (int ks = 0; ks < 4; ++ks) {
            bfrag8 bp = *(const bfrag8*)(&P[nt * 16 + col][0] + ks * 32 + quad * 8);
            acc = __builtin_amdgcn_mfma_f32_16x16x32_bf16(ak[ks], bp, acc, 0, 0, 0);
        }
        if (quad < 2) {
            #pragma unroll
            for (int r = 0; r < 4; ++r) {
                int h = quad * 4 + r, k = nt * 16 + col;
                SC[h][k] = (g < 0) ? -1e30f : acc[r] * 0.25f;
            }
        }
    }
    __syncthreads();

    // softmax: 128 threads, h = t>>4, 2 values each, 16-lane shuffle groups
    {
        int h = t >> 4, sub = t & 15;
        float v0 = SC[h][sub], v1 = SC[h][sub + 16];
        float m = fmaxf(v0, v1);
        m = fmaxf(m, __shfl_xor(m, 1));
        m = fmaxf(m, __shfl_xor(m, 2));
        m = fmaxf(m, __shfl_xor(m, 4));
        m = fmaxf(m, __shfl_xor(m, 8));
        float e0 = __expf(v0 - m), e1 = __expf(v1 - m);
        float s = e0 + e1;
        s += __shfl_xor(s, 1);
        s += __shfl_xor(s, 2);
        s += __shfl_xor(s, 4);
        s += __shfl_xor(s, 8);
        float inv = 1.0f / s;
        SC[h][sub]      = e0 * inv;
        SC[h][sub + 16] = e1 * inv;
    }
    __syncthreads();

    // PV: wave wv handles nt = wv*4 .. wv*4+3
    {
        union { bfrag8 f; unsigned u32v[4]; } at8;
        #pragma unroll
        for (int j = 0; j < 4; ++j) {
            float a0 = SC[col & 7][quad * 8 + 2*j];
            float a1 = SC[col & 7][quad * 8 + 2*j + 1];
            at8.u32v[j] = cvtpk(a0, a1);
        }
        #pragma unroll
        for (int i = 0; i < 4; ++i) {
            int nt = wv * 4 + i;
            union { bfrag8 f; unsigned short u[8]; } bt;
            #pragma unroll
            for (int j = 0; j < 8; ++j)
                bt.u[j] = P[quad * 8 + j][nt * 16 + col];
            f32x4 d = {0.f, 0.f, 0.f, 0.f};
            d = __builtin_amdgcn_mfma_f32_16x16x32_bf16(at8.f, bt.f, d, 0, 0, 0);
            // z output aliased into P rows 0..7 of this (now dead) column stripe
            if (quad < 2) {
                #pragma unroll
                for (int r = 0; r < 4; ++r)
                    P[quad * 4 + r][nt * 16 + col] = f2bf(d[r]);
            }
        }
    }
    __syncthreads();

    {
        unsigned* zout = (unsigned*)(Qk + (long)n * 1024);
        #pragma unroll
        for (int j = 0; j < 4; ++j) {
            int idx = t + j * 128;
            zout[idx] = *(const unsigned*)&P[idx >> 6][(idx & 63) * 2];
        }
    }
}

// ---- out-proj from z: y1 = feat + z @ M^T + ob2 ; bn1 stats ----
// M in fragment order -> each b-group load is ONE contiguous 1KB per wave.
// 2-stage register double-buffer + sched_barrier(0) pins load batches
// (plain source batching got sunk by the scheduler: VGPR stayed 52, R7).
template <typename T>
__global__ __launch_bounds__(256) void k_outproj(
    const float* __restrict__ wsW, const unsigned short* __restrict__ wsB,
    const void* __restrict__ featv, const int* __restrict__ flagp,
    const unsigned short* __restrict__ Z, T* __restrict__ Y, float* __restrict__ acc_s)
{
    __shared__ float syf[32][132];
    int t = threadIdx.x;
    int row0 = blockIdx.x * 32;
    const int bf = *flagp;
    int lane = t & 63, w = t >> 6;
    int col = lane & 15, quad = lane >> 4;
    const float* ob2 = (const float*)(wsB + B_OB2);
    int mt = w & 1, ntb = w >> 1;
    f32x4 acc[4] = {{0,0,0,0},{0,0,0,0},{0,0,0,0},{0,0,0,0}};
    const unsigned short* zrow = Z + (long)(row0 + mt*16 + col) * 1024 + quad * 8;
    const unsigned short* mbase = wsB + B_M + lane * 8;
    #pragma unroll
    for (int ktc = 0; ktc < 4; ++ktc) {
        bfrag8 a[8];
        #pragma unroll
        for (int j = 0; j < 8; ++j)
            a[j] = *(const bfrag8*)(zrow + (ktc * 8 + j) * 32);
        __builtin_amdgcn_sched_barrier(0);
        bfrag8 bA[8], bB[8];
#define LOADB(dst, ii) { const unsigned short* mb = mbase + ((ntb + 2*(ii))*32 + ktc*8)*512; \
    _Pragma("unroll") for (int j = 0; j < 8; ++j) dst[j] = *(const bfrag8*)(mb + j*512); }
#define MFMA8(buf, ii) { _Pragma("unroll") for (int j = 0; j < 8; ++j) \
    acc[ii] = __builtin_amdgcn_mfma_f32_16x16x32_bf16(a[j], buf[j], acc[ii], 0, 0, 0); }
        LOADB(bA, 0)
        __builtin_amdgcn_sched_barrier(0);
        LOADB(bB, 1)
        __builtin_amdgcn_sched_barrier(0);
        MFMA8(bA, 0)
        LOADB(bA, 2)
        __builtin_amdgcn_sched_barrier(0);
        MFMA8(bB, 1)
        LOADB(bB, 3)
        __builtin_amdgcn_sched_barrier(0);
        MFMA8(bA, 2)
        MFMA8(bB, 3)
#undef LOADB
#undef MFMA8
    }
    #pragma unroll
    for (int i = 0; i < 4; ++i) {
        int n0 = (ntb + 2 * i) * 16;
        #pragma unroll
        for (int r = 0; r < 4; ++r) {
            int m = mt*16 + quad*4 + r;
            int n = n0 + col;
            syf[m][n] = acc[i][r] + ob2[n] + ldF(featv, (long)(row0+m)*C + n, bf);
        }
    }
    __syncthreads();
    for (int i = t; i < 32 * C; i += 256)
        stE(Y, (long)row0 * C + i, syf[i>>7][i&127]);
    if (t < C) {
        float s = 0.f, sq = 0.f;
        for (int r = 0; r < 32; ++r) { float v = syf[r][t]; s += v; sq += v*v; }
        atomicAdd(&acc_s[t], s);
        atomicAdd(&acc_s[C + t], sq);
    }
}

// ---- bn1 + FFN + residual + bn2 stats (MFMA, FF split in 2 halves) ----
// Weight-load batches pinned with sched_barrier(0).
template <typename T>
__global__ __launch_bounds__(256) void k_ffn(
    const float* __restrict__ wsW, const unsigned short* __restrict__ wsB,
    T* __restrict__ Y, const float* __restrict__ acc1, float* __restrict__ acc2)
{
    __shared__ __align__(16) unsigned short sxb[32][136];
    __shared__ __align__(16) unsigned short sh[32][264];   // one FF half
    __shared__ float nsc[C], nsh[C];
    float (*syf)[132] = (float(*)[132])sh;                 // aliased after last half
    int t = threadIdx.x;
    int row0 = blockIdx.x * 32;
    if (t < C) {
        float m = acc1[t] * (1.0f/NPTS);
        float v = acc1[C+t] * (1.0f/NPTS) - m*m;
        float rs = rsqrtf(v + EPS);
        float sc = rs * wsW[OFF_N1G + t];
        nsc[t] = sc;
        nsh[t] = wsW[OFF_N1B + t] - m * sc;
    }
    __syncthreads();
    for (int i = t; i < 32 * C; i += 256) {
        int c = i & 127;
        sxb[i>>7][c] = f2bf(ldE(Y, (long)row0 * C + i) * nsc[c] + nsh[c]);
    }
    __syncthreads();
    int lane = t & 63, w = t >> 6;
    int col = lane & 15, quad = lane >> 4;
    int mtw = w & 1, ntb = w >> 1;
    f32x4 accT[4] = {{0,0,0,0},{0,0,0,0},{0,0,0,0},{0,0,0,0}};
    #pragma unroll
    for (int half = 0; half < 2; ++half) {
        // GEMM1: 32 x [C] @ lin1[half*256 .. +256]^T -> sh (relu, bf16)
        for (int tid = w; tid < 32; tid += 4) {
            int mt = tid & 1, nt = tid >> 1, n0 = nt * 16;
            f32x4 acc = {0.f, 0.f, 0.f, 0.f};
            const unsigned short* aB = &sxb[mt*16][0];
            const unsigned short* bB = wsB + B_LIN1 + (half * 256 + n0) * C;
            bfrag8 bv4[4];
            #pragma unroll
            for (int kt = 0; kt < 4; ++kt)
                bv4[kt] = ldfrag(bB, C, lane, kt*32);
            __builtin_amdgcn_sched_barrier(0);
            #pragma unroll
            for (int kt = 0; kt < 4; ++kt) {
                bfrag8 a = ldfrag(aB, 136, lane, kt*32);
                acc = __builtin_amdgcn_mfma_f32_16x16x32_bf16(a, bv4[kt], acc, 0, 0, 0);
            }
            #pragma unroll
            for (int r = 0; r < 4; ++r) {
                int m = mt*16 + quad*4 + r;
                int nf = half * 256 + n0 + col;
                sh[m][n0 + col] = f2bf(fmaxf(acc[r] + wsW[OFF_LIN1_B + nf], 0.f));
            }
        }
        __syncthreads();
        // GEMM2 partial-K accumulate over this half (b batched + pinned)
        #pragma unroll
        for (int i = 0; i < 4; ++i) {
            int mt = mtw, n0 = (ntb + 2 * i) * 16;
            const unsigned short* aB = &sh[mt*16][0];
            const unsigned short* bB = wsB + B_LIN2 + (n0 + col) * FF + half * 256;
            bfrag8 b[8];
            #pragma unroll
            for (int kt = 0; kt < 8; ++kt)
                b[kt] = *(const bfrag8*)(bB + kt * 32 + quad * 8);
            __builtin_amdgcn_sched_barrier(0);
            #pragma unroll
            for (int kt = 0; kt < 8; ++kt) {
                bfrag8 a = ldfrag(aB, 264, lane, kt*32);
                accT[i] = __builtin_amdgcn_mfma_f32_16x16x32_bf16(a, b[kt], accT[i], 0, 0, 0);
            }
        }
        __syncthreads();
    }
    #pragma unroll
    for (int i = 0; i < 4; ++i) {
        int n0 = (ntb + 2 * i) * 16;
        #pragma unroll
        for (int r = 0; r < 4; ++r) {
            int m = mtw*16 + quad*4 + r;
            int n = n0 + col;
            syf[m][n] = accT[i][r] + wsW[OFF_LIN2_B + n] + bf2f(sxb[m][n]);
        }
    }
    __syncthreads();
    for (int i = t; i < 32 * C; i += 256)
        stE(Y, (long)row0 * C + i, syf[i>>7][i&127]);
    if (t < C) {
        float s = 0.f, sq = 0.f;
        for (int r = 0; r < 32; ++r) { float v = syf[r][t]; s += v; sq += v*v; }
        atomicAdd(&acc2[t], s);
        atomicAdd(&acc2[C+t], sq);
    }
}

// ---- bn2 + output linear + bn3 stats (MFMA, b batched + pinned) ----
template <typename T>
__global__ __launch_bounds__(256) void k_outl(
    const float* __restrict__ wsW, const unsigned short* __restrict__ wsB,
    T* __restrict__ Y, const float* __restrict__ acc2, float* __restrict__ acc3)
{
    __shared__ __align__(16) unsigned short sxb[32][136];
    __shared__ float syf[32][132];
    __shared__ float nsc[C], nsh[C];
    int t = threadIdx.x;
    int row0 = blockIdx.x * 32;
    if (t < C) {
        float m = acc2[t] * (1.0f/NPTS);
        float v = acc2[C+t] * (1.0f/NPTS) - m*m;
        float rs = rsqrtf(v + EPS);
        float sc = rs * wsW[OFF_N2G + t];
        nsc[t] = sc;
        nsh[t] = wsW[OFF_N2B + t] - m * sc;
    }
    __syncthreads();
    for (int i = t; i < 32 * C; i += 256) {
        int c = i & 127;
        sxb[i>>7][c] = f2bf(ldE(Y, (long)row0 * C + i) * nsc[c] + nsh[c]);
    }
    __syncthreads();
    int lane = t & 63, w = t >> 6;
    int col = lane & 15, quad = lane >> 4;
    for (int tid = w; tid < 16; tid += 4) {
        int mt = tid & 1, nt = tid >> 1, n0 = nt * 16;
        f32x4 acc = {0.f, 0.f, 0.f, 0.f};
        const unsigned short* aB = &sxb[mt*16][0];
        const unsigned short* bB = wsB + B_OUTL + n0 * C;
        bfrag8 bv4[4];
        #pragma unroll
        for (int kt = 0; kt < 4; ++kt)
            bv4[kt] = ldfrag(bB, C, lane, kt*32);
        __builtin_amdgcn_sched_barrier(0);
        #pragma unroll
        for (int kt = 0; kt < 4; ++kt) {
            bfrag8 a = ldfrag(aB, 136, lane, kt*32);
            acc = __builtin_amdgcn_mfma_f32_16x16x32_bf16(a, bv4[kt], acc, 0, 0, 0);
        }
        #pragma unroll
        for (int r = 0; r < 4; ++r) {
            int m = mt*16 + quad*4 + r;
            int n = n0 + col;
            syf[m][n] = acc[r] + wsW[OFF_OUTL_B + n];
        }
    }
    __syncthreads();
    for (int i = t; i < 32 * CO; i += 256)
        stE(Y, (long)row0 * CO + i, syf[i>>7][i&127]);
    if (t < CO) {
        float s = 0.f, sq = 0.f;
        for (int r = 0; r < 32; ++r) { float v = syf[r][t]; s += v; sq += v*v; }
        atomicAdd(&acc3[t], s);
        atomicAdd(&acc3[CO+t], sq);
    }
}

// ---- final BN + relu -> output ----
template <typename T>
__global__ __launch_bounds__(256) void k_final(
    const float* __restrict__ wsW, const T* __restrict__ Y,
    const float* __restrict__ acc3, const int* __restrict__ flagp,
    void* __restrict__ out)
{
    long i = (long)blockIdx.x * 256 + threadIdx.x;
    int c = (int)(i & (CO-1));
    float m = acc3[c] * (1.0f/NPTS);
    float v = acc3[CO+c] * (1.0f/NPTS) - m*m;
    float rs = rsqrtf(v + EPS);
    float y = (ldE(Y, i) - m) * rs * wsW[OFF_BOG + c] + wsW[OFF_BOB + c];
    y = fmaxf(y, 0.f);
    if (*flagp) ((unsigned short*)out)[i] = f2bf(y);
    else        ((float*)out)[i] = y;
}

extern "C" void kernel_launch(void* const* d_in, const int* in_sizes, int n_in,
                              void* d_out, int out_size, void* d_ws, size_t ws_size,
                              hipStream_t stream)
{
    char* base = (char*)d_ws;
    float* wsW = (float*)base;
    float* acc1 = wsW + WTOTAL;
    float* acc2 = acc1 + 256;
    float* acc3 = acc2 + 256;
    int* flagp = (int*)(wsW + WTOTAL + 768);
    float* coords = wsW + WTOTAL + 776;
    unsigned short* wsB = (unsigned short*)(base + OFF_WB_BYTES);

    const void* featv = d_in[0];
    const int* indices = (const int*)d_in[1];
    const int* key_idx = (const int*)d_in[2];

    hipMemsetAsync(acc1, 0, 768 * sizeof(float), stream);
    k_detect<<<1, 256, 0, stream>>>((const unsigned short*)d_in[0], flagp);

    static const int cnt[20] = {49152,384,16384,128,384,128,384,128,128,128,
                                128,128,65536,512,65536,128,16384,128,128,128};
    static const int bofs[20] = {B_INPROJ,-1,B_OUTW,-1,-1,-1,-1,-1,-1,-1,
                                 -1,-1,B_LIN1,-1,B_LIN2,-1,B_OUTL,-1,-1,-1};
    WTab tab;
    int off = 0;
    for (int j = 0; j < 20; ++j) {
        tab.src[j] = d_in[3 + j];
        tab.beg[j] = off;
        tab.end[j] = off + cnt[j];
        tab.bo[j] = bofs[j];
        off += cnt[j];
    }
    k_cvt_weights<<<WTOTAL/256, 256, 0, stream>>>(tab, wsW, wsB, flagp);
    k_mkmat<<<128, 256, 0, stream>>>(wsW, wsB);

    size_t bigN = (size_t)NPTS * C;
    bool f32mode = (ws_size >= OFF_BIG_BYTES + QK_BYTES + bigN * 4);

    unsigned short* Qk = (unsigned short*)(base + OFF_BIG_BYTES);

    k_proj<<<NPTS/32, 256, 0, stream>>>(wsW, wsB, featv, flagp, indices, coords, Qk);
    k_attn<<<NPTS, 128, 0, stream>>>(wsW, wsB, coords, key_idx, featv, flagp, Qk);

    if (f32mode) {
        float* Y = (float*)(base + OFF_BIG_BYTES + QK_BYTES);
        k_outproj<float><<<NPTS/32, 256, 0, stream>>>(wsW, wsB, featv, flagp, Qk, Y, acc1);
        k_ffn<float><<<NPTS/32, 256, 0, stream>>>(wsW, wsB, Y, acc1, acc2);
        k_outl<float><<<NPTS/32, 256, 0, stream>>>(wsW, wsB, Y, acc2, acc3);
        k_final<float><<<(NPTS*CO)/256, 256, 0, stream>>>(wsW, Y, acc3, flagp, d_out);
    } else {
        unsigned short* Y = (unsigned short*)(base + OFF_BIG_BYTES + QK_BYTES);
        k_outproj<unsigned short><<<NPTS/32, 256, 0, stream>>>(wsW, wsB, featv, flagp, Qk, Y, acc1);
        k_ffn<unsigned short><<<NPTS/32, 256, 0, stream>>>(wsW, wsB, Y, acc1, acc2);
        k_outl<unsigned short><<<NPTS/32, 256, 0, stream>>>(wsW, wsB, Y, acc2, acc3);
        k_final<unsigned short><<<(NPTS*CO)/256, 256, 0, stream>>>(wsW, Y, acc3, flagp, d_out);
    }
}

// Round 20
// 603.036 us; speedup vs baseline: 1.0758x; 1.0758x over previous
//
#include <hip/hip_runtime.h>

#define NPTS 60000
#define C 128
#define K 32
#define FF 512
#define CO 128
#define H 8
#define DH 16
#define EPS 1e-5f

// ---- fp32 weight layout (float elements) ----
constexpr int OFF_INPROJ_W = 0;          // 384*128
constexpr int OFF_INPROJ_B = 49152;      // 384
constexpr int OFF_OUT_W    = 49536;      // 16384
constexpr int OFF_OUT_B    = 65920;      // 128
constexpr int OFF_QPOS_W   = 66048;      // 384
constexpr int OFF_QPOS_B   = 66432;      // 128
constexpr int OFF_KPOS_W   = 66560;      // 384
constexpr int OFF_KPOS_B   = 66944;      // 128
constexpr int OFF_N1G      = 67072;
constexpr int OFF_N1B      = 67200;
constexpr int OFF_N2G      = 67328;
constexpr int OFF_N2B      = 67456;
constexpr int OFF_LIN1_W   = 67584;      // 65536
constexpr int OFF_LIN1_B   = 133120;     // 512
constexpr int OFF_LIN2_W   = 133632;     // 65536
constexpr int OFF_LIN2_B   = 199168;     // 128
constexpr int OFF_OUTL_W   = 199296;     // 16384
constexpr int OFF_OUTL_B   = 215680;     // 128
constexpr int OFF_BOG      = 215808;
constexpr int OFF_BOB      = 215936;
constexpr int WTOTAL       = 216064;

// ---- bf16 weight copies (ushort elements within wsB) ----
constexpr int B_INPROJ = 0;        // 384x128
constexpr int B_OUTW   = 49152;    // 128x128 (layout keep)
constexpr int B_LIN1   = 65536;    // 512x128
constexpr int B_LIN2   = 131072;   // 128x512
constexpr int B_OUTL   = 196608;   // 128x128
constexpr int B_WKT    = 212992;   // 128x128
constexpr int B_KPW4   = 229376;   // 128 x float4 (fp32, 2048 B)
constexpr int B_M      = 230400;   // 128x1024 bf16, FRAGMENT-ORDER (see k_mkmat)
constexpr int B_OB2    = 361472;   // 128 fp32: out_b + outw@bv
constexpr size_t OFF_WB_BYTES  = 1587456;
constexpr size_t OFF_BIG_BYTES = 2310912;
constexpr size_t QK_BYTES = (size_t)NPTS * 1024 * 2;   // qkt rows; reused as z rows

typedef __attribute__((ext_vector_type(8))) short bfrag8;
typedef __attribute__((ext_vector_type(4))) float f32x4;

__device__ __forceinline__ float bf2f(unsigned short s) {
    return __uint_as_float(((unsigned)s) << 16);
}
__device__ __forceinline__ unsigned short f2bf(float f) {
    unsigned u = __float_as_uint(f);
    u += 0x7fffu + ((u >> 16) & 1u);
    return (unsigned short)(u >> 16);
}
__device__ __forceinline__ float ldE(const float* p, long i) { return p[i]; }
__device__ __forceinline__ float ldE(const unsigned short* p, long i) { return bf2f(p[i]); }
__device__ __forceinline__ void stE(float* p, long i, float v) { p[i] = v; }
__device__ __forceinline__ void stE(unsigned short* p, long i, float v) { p[i] = f2bf(v); }
__device__ __forceinline__ float ldF(const void* p, long i, int bf) {
    return bf ? bf2f(((const unsigned short*)p)[i]) : ((const float*)p)[i];
}
__device__ __forceinline__ bfrag8 ldfrag(const unsigned short* base, int stride, int lane, int k0) {
    return *(const bfrag8*)(base + (lane & 15) * stride + k0 + ((lane >> 4) << 3));
}
__device__ __forceinline__ unsigned cvtpk(float lo, float hi) {
    unsigned r;
    asm("v_cvt_pk_bf16_f32 %0, %1, %2" : "=v"(r) : "v"(lo), "v"(hi));
    return r;
}

// ---- dtype probe ----
__global__ __launch_bounds__(256) void k_detect(const unsigned short* __restrict__ f,
                                                int* __restrict__ flag) {
    __shared__ int cnt_s;
    if (threadIdx.x == 0) cnt_s = 0;
    __syncthreads();
    int sane = 0;
    for (int j = 0; j < 16; ++j) {
        unsigned short u = f[threadIdx.x * 16 + j];
        int e = (u >> 7) & 255;
        sane += (u == 0 || (e >= 100 && e <= 142)) ? 1 : 0;
    }
    atomicAdd(&cnt_s, sane);
    __syncthreads();
    if (threadIdx.x == 0) *flag = (cnt_s >= 3686) ? 1 : 0;
}

struct WTab {
    const void* src[20];
    int beg[20];
    int end[20];
    int bo[20];
};

__global__ __launch_bounds__(256) void k_cvt_weights(WTab tab, float* __restrict__ ws,
                                                     unsigned short* __restrict__ wsB,
                                                     const int* __restrict__ flagp) {
    int bf = *flagp;
    int gid = blockIdx.x * 256 + threadIdx.x;
    #pragma unroll
    for (int j = 0; j < 20; ++j) {
        if (gid >= tab.beg[j] && gid < tab.end[j]) {
            int off = gid - tab.beg[j];
            float v;
            unsigned short raw;
            if (bf) { raw = ((const unsigned short*)tab.src[j])[off]; v = bf2f(raw); }
            else    { v = ((const float*)tab.src[j])[off]; raw = f2bf(v); }
            ws[gid] = v;
            if (tab.bo[j] >= 0) wsB[tab.bo[j] + off] = raw;
            if (j == 0 && off >= 16384 && off < 32768) {
                int r = (off >> 7) - 128;
                int c = off & 127;
                wsB[B_WKT + c * C + r] = raw;
            }
            if (j == 6) {
                int c = off / 3, comp = off - 3 * c;
                ((float*)(wsB + B_KPW4))[c * 4 + comp] = v;
            }
            if (j == 7) {
                ((float*)(wsB + B_KPW4))[off * 4 + 3] = v;
            }
        }
    }
}

// ---- precompute M in MFMA-fragment order ; ob2 ----
// M2 layout: for n-tile g=n>>4, k-chunk c=k>>5: element M[n][k] lives at
//   (g*32+c)*512 + lane*8 + (k&7),  lane = ((k&31)>>3)*16 + (n&15)
// so a wave's b-fragment load for (g,c) is ONE contiguous 1KB block.
__global__ __launch_bounds__(256) void k_mkmat(const float* __restrict__ wsW,
                                               unsigned short* __restrict__ wsBmut) {
    int j = blockIdx.x;   // output col n
    int t = threadIdx.x;
    const float* outw = wsW + OFF_OUT_W + j * C;
    #pragma unroll
    for (int i = 0; i < 4; ++i) {
        int idx = t + i * 256;        // k in 0..1023
        int h = idx >> 7, cp = idx & 127;
        float s = 0.f;
        const float* wvh = wsW + OFF_INPROJ_W + (256 + h * 16) * C + cp;
        const float* owh = outw + h * 16;
        #pragma unroll
        for (int d = 0; d < 16; ++d)
            s += owh[d] * wvh[d * C];
        int g = j >> 4, c = idx >> 5, r = idx & 31;
        int lane = ((r >> 3) << 4) + (j & 15);
        wsBmut[B_M + (g * 32 + c) * 512 + lane * 8 + (r & 7)] = f2bf(s);
    }
    if (t == 0) {
        float s = wsW[OFF_OUT_B + j];
        const float* bv = wsW + OFF_INPROJ_B + 256;
        for (int c = 0; c < C; ++c) s += outw[c] * bv[c];
        ((float*)(wsBmut + B_OB2))[j] = s;
    }
}

// ---- fused coords + qpos + Q projection + per-head qkt precompute ----
__global__ __launch_bounds__(256) void k_proj(
    const float* __restrict__ wsW, const unsigned short* __restrict__ wsB,
    const void* __restrict__ featv, const int* __restrict__ flagp,
    const int* __restrict__ indices, float* __restrict__ coords,
    unsigned short* __restrict__ Qk)
{
    __shared__ __align__(16) unsigned short sqb[32][136];
    __shared__ __align__(16) unsigned short sqh[32][136];
    __shared__ __align__(16) unsigned short sqk[2][32][136];
    __shared__ float scd[32][4];
    int t = threadIdx.x;
    int row0 = blockIdx.x * 32;
    const int bf = *flagp;
    if (t < 96) {
        int r = t / 3, j = t - 3 * r;
        int n = row0 + r;
        int srci = (j == 0) ? 3 : (j == 1 ? 2 : 1);
        float vs = (j == 2) ? 0.2f : 0.1f;
        float mn = (j == 2) ? -3.0f : -40.0f;
        float v = ((float)indices[n * 4 + srci] + 0.5f) * vs + mn;
        scd[r][j] = v;
        coords[n * 3 + j] = v;
    }
    __syncthreads();
    const float* qpw = wsW + OFF_QPOS_W;
    const float* qpb = wsW + OFF_QPOS_B;
    for (int i = t; i < 32 * C; i += 256) {
        int r = i >> 7, c = i & 127;
        float x = ldF(featv, (long)row0 * C + i, bf);
        float a = qpb[c] + scd[r][0]*qpw[c*3] + scd[r][1]*qpw[c*3+1] + scd[r][2]*qpw[c*3+2];
        sqb[r][c] = f2bf(x + fmaxf(a, 0.0f));
    }
    __syncthreads();
    int lane = t & 63, w = t >> 6;
    int col = lane & 15, quad = lane >> 4;
    for (int tid = w; tid < 16; tid += 4) {
        int mt = tid & 1, nt = tid >> 1, n0 = nt * 16;
        f32x4 acc = {0.f, 0.f, 0.f, 0.f};
        const unsigned short* aB = &sqb[mt*16][0];
        const unsigned short* bB = wsB + B_INPROJ + n0 * C;
        #pragma unroll
        for (int kt = 0; kt < 4; ++kt) {
            bfrag8 a = ldfrag(aB, 136, lane, kt*32);
            bfrag8 b = ldfrag(bB, C, lane, kt*32);
            acc = __builtin_amdgcn_mfma_f32_16x16x32_bf16(a, b, acc, 0, 0, 0);
        }
        #pragma unroll
        for (int r = 0; r < 4; ++r) {
            int n = n0 + col;
            sqh[mt*16 + quad*4 + r][n] = f2bf(acc[r] + wsW[OFF_INPROJ_B + n]);
        }
    }
    __syncthreads();
    const unsigned short* wkT = wsB + B_WKT;
    bfrag8 zf = {0,0,0,0,0,0,0,0};
    for (int h = 0; h < 8; ++h) {
        for (int tid = w; tid < 16; tid += 4) {
            int mt = tid & 1, nt = tid >> 1, n0 = nt * 16;
            bfrag8 a = zf, b = zf;
            if (quad < 2) {
                a = *(const bfrag8*)(&sqh[mt*16 + col][h*16 + quad*8]);
                b = *(const bfrag8*)(wkT + (n0 + col) * C + h*16 + quad*8);
            }
            f32x4 acc = {0.f, 0.f, 0.f, 0.f};
            acc = __builtin_amdgcn_mfma_f32_16x16x32_bf16(a, b, acc, 0, 0, 0);
            #pragma unroll
            for (int r = 0; r < 4; ++r)
                sqk[h & 1][mt*16 + quad*4 + r][n0 + col] = f2bf(acc[r]);
        }
        __syncthreads();
        for (int i = t; i < 2048; i += 256) {
            int r = i >> 6, cp = i & 63;
            unsigned v = *(const unsigned*)&sqk[h & 1][r][2 * cp];
            ((unsigned*)Qk)[(long)(row0 + r) * 512 + h * 64 + cp] = v;
        }
    }
}

// ---- attention: ONE wave per block (reverted from 2-wave: R11 measured +34%
// HBM traffic / 153->178 us regression — occupancy gain was spent on L2
// thrash). XCD-aware swizzle added: contiguous point-ranges per XCD so Qk/z
// streams stay in one XCD's L2.
__global__ __launch_bounds__(64, 4) void k_attn(
    const float* __restrict__ wsW, const unsigned short* __restrict__ wsB,
    const float* __restrict__ coords, const int* __restrict__ key_idx,
    const void* __restrict__ featv, const int* __restrict__ flagp,
    unsigned short* __restrict__ Qk)
{
    __shared__ __align__(16) unsigned short P[32][136];
    __shared__ __align__(16) float SC[8][36];
    __shared__ __align__(16) float REL[32][4];
    __shared__ __align__(16) int   GS[32];

    int l = threadIdx.x;
    int bid = blockIdx.x;
    int n = (bid & 7) * (NPTS / 8) + (bid >> 3);   // bijective: 60000 % 8 == 0
    int col = l & 15, quad = l >> 4;
    int c0 = 2 * l;
    const int bf = *flagp;

    const float* kpwp = wsW + OFF_KPOS_W;
    float kw00 = kpwp[c0*3],   kw01 = kpwp[c0*3+1], kw02 = kpwp[c0*3+2];
    float kw10 = kpwp[c0*3+3], kw11 = kpwp[c0*3+4], kw12 = kpwp[c0*3+5];
    float kb0 = wsW[OFF_KPOS_B + c0], kb1 = wsW[OFF_KPOS_B + c0 + 1];

    if (l < 32) GS[l] = key_idx[n * K + l];
    float cenx = coords[n*3+0], ceny = coords[n*3+1], cenz = coords[n*3+2];
    bfrag8 ak[4];
    {
        const unsigned short* qkrow = Qk + (long)n * 1024 + (col & 7) * 128;
        #pragma unroll
        for (int ks = 0; ks < 4; ++ks)
            ak[ks] = *(const bfrag8*)(qkrow + ks * 32 + quad * 8);
    }
    if (l < 32) {
        int gc = max(GS[l], 0);
        REL[l][0] = coords[gc*3+0] - cenx;
        REL[l][1] = coords[gc*3+1] - ceny;
        REL[l][2] = coords[gc*3+2] - cenz;
        REL[l][3] = 0.f;
    }
    __syncthreads();

    if (bf) {
        const unsigned* xb = (const unsigned*)featv;
        unsigned xv[32];
        #pragma unroll
        for (int k = 0; k < K; ++k) {
            int gcs = __builtin_amdgcn_readfirstlane(max(GS[k], 0));
            xv[k] = xb[(long)gcs * 64 + l];
        }
        #pragma unroll
        for (int k = 0; k < K; ++k) {
            float4 rr = *(const float4*)&REL[k][0];
            float p0 = bf2f((unsigned short)xv[k])
                     + fmaxf(kb0 + rr.x*kw00 + rr.y*kw01 + rr.z*kw02, 0.f);
            float p1 = bf2f((unsigned short)(xv[k] >> 16))
                     + fmaxf(kb1 + rr.x*kw10 + rr.y*kw11 + rr.z*kw12, 0.f);
            *(unsigned*)&P[k][c0] = cvtpk(p0, p1);
        }
    } else {
        const float2* xf = (const float2*)featv;
        #pragma unroll
        for (int kc = 0; kc < K; kc += 16) {
            float2 xv[16];
            #pragma unroll
            for (int j = 0; j < 16; ++j) {
                int gcs = __builtin_amdgcn_readfirstlane(max(GS[kc + j], 0));
                xv[j] = xf[(long)gcs * 64 + l];
            }
            #pragma unroll
            for (int j = 0; j < 16; ++j) {
                int k = kc + j;
                float4 rr = *(const float4*)&REL[k][0];
                float p0 = xv[j].x + fmaxf(kb0 + rr.x*kw00 + rr.y*kw01 + rr.z*kw02, 0.f);
                float p1 = xv[j].y + fmaxf(kb1 + rr.x*kw10 + rr.y*kw11 + rr.z*kw12, 0.f);
                *(unsigned*)&P[k][c0] = cvtpk(p0, p1);
            }
        }
    }
    __syncthreads();

    #pragma unroll
    for (int nt = 0; nt < 2; ++nt) {
        int g = GS[nt * 16 + col];
        f32x4 acc = {0.f, 0.f, 0.f, 0.f};
        #pragma unroll
        for (int ks = 0; ks < 4; ++ks) {
            bfrag8 bp = *(const bfrag8*)(&P[nt * 16 + col][0] + ks * 32 + quad * 8);
            acc = __builtin_amdgcn_mfma_f32_16x16x32_bf16(ak[ks], bp, acc, 0, 0, 0);
        }
        if (quad < 2) {
            #pragma unroll
            for (int r = 0; r < 4; ++r) {
                int h = quad * 4 + r, k = nt * 16 + col;
                SC[h][k] = (g < 0) ? -1e30f : acc[r] * 0.25f;
            }
        }
    }
    __syncthreads();

    {
        int h = l >> 3, sub = l & 7;
        float v0 = SC[h][sub],      v1 = SC[h][sub + 8];
        float v2 = SC[h][sub + 16], v3 = SC[h][sub + 24];
        float m = fmaxf(fmaxf(v0, v1), fmaxf(v2, v3));
        m = fmaxf(m, __shfl_xor(m, 1));
        m = fmaxf(m, __shfl_xor(m, 2));
        m = fmaxf(m, __shfl_xor(m, 4));
        float e0 = __expf(v0 - m), e1 = __expf(v1 - m), e2 = __expf(v2 - m), e3 = __expf(v3 - m);
        float s = e0 + e1 + e2 + e3;
        s += __shfl_xor(s, 1);
        s += __shfl_xor(s, 2);
        s += __shfl_xor(s, 4);
        float inv = 1.0f / s;
        SC[h][sub]      = e0 * inv;
        SC[h][sub + 8]  = e1 * inv;
        SC[h][sub + 16] = e2 * inv;
        SC[h][sub + 24] = e3 * inv;
    }
    __syncthreads();

    {
        union { bfrag8 f; unsigned u32v[4]; } at8;
        #pragma unroll
        for (int j = 0; j < 4; ++j) {
            float a0 = SC[col & 7][quad * 8 + 2*j];
            float a1 = SC[col & 7][quad * 8 + 2*j + 1];
            at8.u32v[j] = cvtpk(a0, a1);
        }
        #pragma unroll
        for (int nt = 0; nt < 8; ++nt) {
            union { bfrag8 f; unsigned short u[8]; } bt;
            #pragma unroll
            for (int j = 0; j < 8; ++j)
                bt.u[j] = P[quad * 8 + j][nt * 16 + col];
            f32x4 d = {0.f, 0.f, 0.f, 0.f};
            d = __builtin_amdgcn_mfma_f32_16x16x32_bf16(at8.f, bt.f, d, 0, 0, 0);
            // z output aliased into P rows 0..7 of this (now dead) column stripe
            if (quad < 2) {
                #pragma unroll
                for (int r = 0; r < 4; ++r)
                    P[quad * 4 + r][nt * 16 + col] = f2bf(d[r]);
            }
        }
    }
    __syncthreads();

    {
        unsigned* zout = (unsigned*)(Qk + (long)n * 1024);
        #pragma unroll
        for (int j = 0; j < 8; ++j) {
            int idx = l + j * 64;
            zout[idx] = *(const unsigned*)&P[idx >> 6][(idx & 63) * 2];
        }
    }
}

// ---- out-proj from z: y1 = feat + z @ M^T + ob2 ; bn1 stats ----
// M in fragment order -> each b-group load is ONE contiguous 1KB per wave.
// 2-stage register double-buffer + sched_barrier(0) pins load batches
// (plain source batching got sunk by the scheduler: VGPR stayed 52, R7).
template <typename T>
__global__ __launch_bounds__(256) void k_outproj(
    const float* __restrict__ wsW, const unsigned short* __restrict__ wsB,
    const void* __restrict__ featv, const int* __restrict__ flagp,
    const unsigned short* __restrict__ Z, T* __restrict__ Y, float* __restrict__ acc_s)
{
    __shared__ float syf[32][132];
    int t = threadIdx.x;
    int row0 = blockIdx.x * 32;
    const int bf = *flagp;
    int lane = t & 63, w = t >> 6;
    int col = lane & 15, quad = lane >> 4;
    const float* ob2 = (const float*)(wsB + B_OB2);
    int mt = w & 1, ntb = w >> 1;
    f32x4 acc[4] = {{0,0,0,0},{0,0,0,0},{0,0,0,0},{0,0,0,0}};
    const unsigned short* zrow = Z + (long)(row0 + mt*16 + col) * 1024 + quad * 8;
    const unsigned short* mbase = wsB + B_M + lane * 8;
    #pragma unroll
    for (int ktc = 0; ktc < 4; ++ktc) {
        bfrag8 a[8];
        #pragma unroll
        for (int j = 0; j < 8; ++j)
            a[j] = *(const bfrag8*)(zrow + (ktc * 8 + j) * 32);
        __builtin_amdgcn_sched_barrier(0);
        bfrag8 bA[8], bB[8];
#define LOADB(dst, ii) { const unsigned short* mb = mbase + ((ntb + 2*(ii))*32 + ktc*8)*512; \
    _Pragma("unroll") for (int j = 0; j < 8; ++j) dst[j] = *(const bfrag8*)(mb + j*512); }
#define MFMA8(buf, ii) { _Pragma("unroll") for (int j = 0; j < 8; ++j) \
    acc[ii] = __builtin_amdgcn_mfma_f32_16x16x32_bf16(a[j], buf[j], acc[ii], 0, 0, 0); }
        LOADB(bA, 0)
        __builtin_amdgcn_sched_barrier(0);
        LOADB(bB, 1)
        __builtin_amdgcn_sched_barrier(0);
        MFMA8(bA, 0)
        LOADB(bA, 2)
        __builtin_amdgcn_sched_barrier(0);
        MFMA8(bB, 1)
        LOADB(bB, 3)
        __builtin_amdgcn_sched_barrier(0);
        MFMA8(bA, 2)
        MFMA8(bB, 3)
#undef LOADB
#undef MFMA8
    }
    #pragma unroll
    for (int i = 0; i < 4; ++i) {
        int n0 = (ntb + 2 * i) * 16;
        #pragma unroll
        for (int r = 0; r < 4; ++r) {
            int m = mt*16 + quad*4 + r;
            int n = n0 + col;
            syf[m][n] = acc[i][r] + ob2[n] + ldF(featv, (long)(row0+m)*C + n, bf);
        }
    }
    __syncthreads();
    for (int i = t; i < 32 * C; i += 256)
        stE(Y, (long)row0 * C + i, syf[i>>7][i&127]);
    if (t < C) {
        float s = 0.f, sq = 0.f;
        for (int r = 0; r < 32; ++r) { float v = syf[r][t]; s += v; sq += v*v; }
        atomicAdd(&acc_s[t], s);
        atomicAdd(&acc_s[C + t], sq);
    }
}

// ---- bn1 + FFN + residual + bn2 stats (MFMA, FF split in 2 halves) ----
// Weight-load batches pinned with sched_barrier(0).
template <typename T>
__global__ __launch_bounds__(256) void k_ffn(
    const float* __restrict__ wsW, const unsigned short* __restrict__ wsB,
    T* __restrict__ Y, const float* __restrict__ acc1, float* __restrict__ acc2)
{
    __shared__ __align__(16) unsigned short sxb[32][136];
    __shared__ __align__(16) unsigned short sh[32][264];   // one FF half
    __shared__ float nsc[C], nsh[C];
    float (*syf)[132] = (float(*)[132])sh;                 // aliased after last half
    int t = threadIdx.x;
    int row0 = blockIdx.x * 32;
    if (t < C) {
        float m = acc1[t] * (1.0f/NPTS);
        float v = acc1[C+t] * (1.0f/NPTS) - m*m;
        float rs = rsqrtf(v + EPS);
        float sc = rs * wsW[OFF_N1G + t];
        nsc[t] = sc;
        nsh[t] = wsW[OFF_N1B + t] - m * sc;
    }
    __syncthreads();
    for (int i = t; i < 32 * C; i += 256) {
        int c = i & 127;
        sxb[i>>7][c] = f2bf(ldE(Y, (long)row0 * C + i) * nsc[c] + nsh[c]);
    }
    __syncthreads();
    int lane = t & 63, w = t >> 6;
    int col = lane & 15, quad = lane >> 4;
    int mtw = w & 1, ntb = w >> 1;
    f32x4 accT[4] = {{0,0,0,0},{0,0,0,0},{0,0,0,0},{0,0,0,0}};
    #pragma unroll
    for (int half = 0; half < 2; ++half) {
        // GEMM1: 32 x [C] @ lin1[half*256 .. +256]^T -> sh (relu, bf16)
        for (int tid = w; tid < 32; tid += 4) {
            int mt = tid & 1, nt = tid >> 1, n0 = nt * 16;
            f32x4 acc = {0.f, 0.f, 0.f, 0.f};
            const unsigned short* aB = &sxb[mt*16][0];
            const unsigned short* bB = wsB + B_LIN1 + (half * 256 + n0) * C;
            bfrag8 bv4[4];
            #pragma unroll
            for (int kt = 0; kt < 4; ++kt)
                bv4[kt] = ldfrag(bB, C, lane, kt*32);
            __builtin_amdgcn_sched_barrier(0);
            #pragma unroll
            for (int kt = 0; kt < 4; ++kt) {
                bfrag8 a = ldfrag(aB, 136, lane, kt*32);
                acc = __builtin_amdgcn_mfma_f32_16x16x32_bf16(a, bv4[kt], acc, 0, 0, 0);
            }
            #pragma unroll
            for (int r = 0; r < 4; ++r) {
                int m = mt*16 + quad*4 + r;
                int nf = half * 256 + n0 + col;
                sh[m][n0 + col] = f2bf(fmaxf(acc[r] + wsW[OFF_LIN1_B + nf], 0.f));
            }
        }
        __syncthreads();
        // GEMM2 partial-K accumulate over this half (b batched + pinned)
        #pragma unroll
        for (int i = 0; i < 4; ++i) {
            int mt = mtw, n0 = (ntb + 2 * i) * 16;
            const unsigned short* aB = &sh[mt*16][0];
            const unsigned short* bB = wsB + B_LIN2 + (n0 + col) * FF + half * 256;
            bfrag8 b[8];
            #pragma unroll
            for (int kt = 0; kt < 8; ++kt)
                b[kt] = *(const bfrag8*)(bB + kt * 32 + quad * 8);
            __builtin_amdgcn_sched_barrier(0);
            #pragma unroll
            for (int kt = 0; kt < 8; ++kt) {
                bfrag8 a = ldfrag(aB, 264, lane, kt*32);
                accT[i] = __builtin_amdgcn_mfma_f32_16x16x32_bf16(a, b[kt], accT[i], 0, 0, 0);
            }
        }
        __syncthreads();
    }
    #pragma unroll
    for (int i = 0; i < 4; ++i) {
        int n0 = (ntb + 2 * i) * 16;
        #pragma unroll
        for (int r = 0; r < 4; ++r) {
            int m = mtw*16 + quad*4 + r;
            int n = n0 + col;
            syf[m][n] = accT[i][r] + wsW[OFF_LIN2_B + n] + bf2f(sxb[m][n]);
        }
    }
    __syncthreads();
    for (int i = t; i < 32 * C; i += 256)
        stE(Y, (long)row0 * C + i, syf[i>>7][i&127]);
    if (t < C) {
        float s = 0.f, sq = 0.f;
        for (int r = 0; r < 32; ++r) { float v = syf[r][t]; s += v; sq += v*v; }
        atomicAdd(&acc2[t], s);
        atomicAdd(&acc2[C+t], sq);
    }
}

// ---- bn2 + output linear + bn3 stats (MFMA, b batched + pinned) ----
template <typename T>
__global__ __launch_bounds__(256) void k_outl(
    const float* __restrict__ wsW, const unsigned short* __restrict__ wsB,
    T* __restrict__ Y, const float* __restrict__ acc2, float* __restrict__ acc3)
{
    __shared__ __align__(16) unsigned short sxb[32][136];
    __shared__ float syf[32][132];
    __shared__ float nsc[C], nsh[C];
    int t = threadIdx.x;
    int row0 = blockIdx.x * 32;
    if (t < C) {
        float m = acc2[t] * (1.0f/NPTS);
        float v = acc2[C+t] * (1.0f/NPTS) - m*m;
        float rs = rsqrtf(v + EPS);
        float sc = rs * wsW[OFF_N2G + t];
        nsc[t] = sc;
        nsh[t] = wsW[OFF_N2B + t] - m * sc;
    }
    __syncthreads();
    for (int i = t; i < 32 * C; i += 256) {
        int c = i & 127;
        sxb[i>>7][c] = f2bf(ldE(Y, (long)row0 * C + i) * nsc[c] + nsh[c]);
    }
    __syncthreads();
    int lane = t & 63, w = t >> 6;
    int col = lane & 15, quad = lane >> 4;
    for (int tid = w; tid < 16; tid += 4) {
        int mt = tid & 1, nt = tid >> 1, n0 = nt * 16;
        f32x4 acc = {0.f, 0.f, 0.f, 0.f};
        const unsigned short* aB = &sxb[mt*16][0];
        const unsigned short* bB = wsB + B_OUTL + n0 * C;
        bfrag8 bv4[4];
        #pragma unroll
        for (int kt = 0; kt < 4; ++kt)
            bv4[kt] = ldfrag(bB, C, lane, kt*32);
        __builtin_amdgcn_sched_barrier(0);
        #pragma unroll
        for (int kt = 0; kt < 4; ++kt) {
            bfrag8 a = ldfrag(aB, 136, lane, kt*32);
            acc = __builtin_amdgcn_mfma_f32_16x16x32_bf16(a, bv4[kt], acc, 0, 0, 0);
        }
        #pragma unroll
        for (int r = 0; r < 4; ++r) {
            int m = mt*16 + quad*4 + r;
            int n = n0 + col;
            syf[m][n] = acc[r] + wsW[OFF_OUTL_B + n];
        }
    }
    __syncthreads();
    for (int i = t; i < 32 * CO; i += 256)
        stE(Y, (long)row0 * CO + i, syf[i>>7][i&127]);
    if (t < CO) {
        float s = 0.f, sq = 0.f;
        for (int r = 0; r < 32; ++r) { float v = syf[r][t]; s += v; sq += v*v; }
        atomicAdd(&acc3[t], s);
        atomicAdd(&acc3[CO+t], sq);
    }
}

// ---- final BN + relu -> output ----
template <typename T>
__global__ __launch_bounds__(256) void k_final(
    const float* __restrict__ wsW, const T* __restrict__ Y,
    const float* __restrict__ acc3, const int* __restrict__ flagp,
    void* __restrict__ out)
{
    long i = (long)blockIdx.x * 256 + threadIdx.x;
    int c = (int)(i & (CO-1));
    float m = acc3[c] * (1.0f/NPTS);
    float v = acc3[CO+c] * (1.0f/NPTS) - m*m;
    float rs = rsqrtf(v + EPS);
    float y = (ldE(Y, i) - m) * rs * wsW[OFF_BOG + c] + wsW[OFF_BOB + c];
    y = fmaxf(y, 0.f);
    if (*flagp) ((unsigned short*)out)[i] = f2bf(y);
    else        ((float*)out)[i] = y;
}

extern "C" void kernel_launch(void* const* d_in, const int* in_sizes, int n_in,
                              void* d_out, int out_size, void* d_ws, size_t ws_size,
                              hipStream_t stream)
{
    char* base = (char*)d_ws;
    float* wsW = (float*)base;
    float* acc1 = wsW + WTOTAL;
    float* acc2 = acc1 + 256;
    float* acc3 = acc2 + 256;
    int* flagp = (int*)(wsW + WTOTAL + 768);
    float* coords = wsW + WTOTAL + 776;
    unsigned short* wsB = (unsigned short*)(base + OFF_WB_BYTES);

    const void* featv = d_in[0];
    const int* indices = (const int*)d_in[1];
    const int* key_idx = (const int*)d_in[2];

    hipMemsetAsync(acc1, 0, 768 * sizeof(float), stream);
    k_detect<<<1, 256, 0, stream>>>((const unsigned short*)d_in[0], flagp);

    static const int cnt[20] = {49152,384,16384,128,384,128,384,128,128,128,
                                128,128,65536,512,65536,128,16384,128,128,128};
    static const int bofs[20] = {B_INPROJ,-1,B_OUTW,-1,-1,-1,-1,-1,-1,-1,
                                 -1,-1,B_LIN1,-1,B_LIN2,-1,B_OUTL,-1,-1,-1};
    WTab tab;
    int off = 0;
    for (int j = 0; j < 20; ++j) {
        tab.src[j] = d_in[3 + j];
        tab.beg[j] = off;
        tab.end[j] = off + cnt[j];
        tab.bo[j] = bofs[j];
        off += cnt[j];
    }
    k_cvt_weights<<<WTOTAL/256, 256, 0, stream>>>(tab, wsW, wsB, flagp);
    k_mkmat<<<128, 256, 0, stream>>>(wsW, wsB);

    size_t bigN = (size_t)NPTS * C;
    bool f32mode = (ws_size >= OFF_BIG_BYTES + QK_BYTES + bigN * 4);

    unsigned short* Qk = (unsigned short*)(base + OFF_BIG_BYTES);

    k_proj<<<NPTS/32, 256, 0, stream>>>(wsW, wsB, featv, flagp, indices, coords, Qk);
    k_attn<<<NPTS, 64, 0, stream>>>(wsW, wsB, coords, key_idx, featv, flagp, Qk);

    if (f32mode) {
        float* Y = (float*)(base + OFF_BIG_BYTES + QK_BYTES);
        k_outproj<float><<<NPTS/32, 256, 0, stream>>>(wsW, wsB, featv, flagp, Qk, Y, acc1);
        k_ffn<float><<<NPTS/32, 256, 0, stream>>>(wsW, wsB, Y, acc1, acc2);
        k_outl<float><<<NPTS/32, 256, 0, stream>>>(wsW, wsB, Y, acc2, acc3);
        k_final<float><<<(NPTS*CO)/256, 256, 0, stream>>>(wsW, Y, acc3, flagp, d_out);
    } else {
        unsigned short* Y = (unsigned short*)(base + OFF_BIG_BYTES + QK_BYTES);
        k_outproj<unsigned short><<<NPTS/32, 256, 0, stream>>>(wsW, wsB, featv, flagp, Qk, Y, acc1);
        k_ffn<unsigned short><<<NPTS/32, 256, 0, stream>>>(wsW, wsB, Y, acc1, acc2);
        k_outl<unsigned short><<<NPTS/32, 256, 0, stream>>>(wsW, wsB, Y, acc2, acc3);
        k_final<unsigned short><<<(NPTS*CO)/256, 256, 0, stream>>>(wsW, Y, acc3, flagp, d_out);
    }
}

// Round 22
// 536.467 us; speedup vs baseline: 1.2093x; 1.1241x over previous
//
#include <hip/hip_runtime.h>

#define NPTS 60000
#define C 128
#define K 32
#define FF 512
#define CO 128
#define H 8
#define DH 16
#define EPS 1e-5f

// ---- fp32 weight layout (float elements) ----
constexpr int OFF_INPROJ_W = 0;          // 384*128
constexpr int OFF_INPROJ_B = 49152;      // 384
constexpr int OFF_OUT_W    = 49536;      // 16384
constexpr int OFF_OUT_B    = 65920;      // 128
constexpr int OFF_QPOS_W   = 66048;      // 384
constexpr int OFF_QPOS_B   = 66432;      // 128
constexpr int OFF_KPOS_W   = 66560;      // 384
constexpr int OFF_KPOS_B   = 66944;      // 128
constexpr int OFF_N1G      = 67072;
constexpr int OFF_N1B      = 67200;
constexpr int OFF_N2G      = 67328;
constexpr int OFF_N2B      = 67456;
constexpr int OFF_LIN1_W   = 67584;      // 65536
constexpr int OFF_LIN1_B   = 133120;     // 512
constexpr int OFF_LIN2_W   = 133632;     // 65536
constexpr int OFF_LIN2_B   = 199168;     // 128
constexpr int OFF_OUTL_W   = 199296;     // 16384
constexpr int OFF_OUTL_B   = 215680;     // 128
constexpr int OFF_BOG      = 215808;
constexpr int OFF_BOB      = 215936;
constexpr int WTOTAL       = 216064;

// ---- bf16 weight copies (ushort elements within wsB) ----
// LIN1 / LIN2 / OUTL are stored in MFMA FRAGMENT ORDER (R20: k_ffn showed
// the outproj disease — every pipe idle, 16-way scattered b-loads; same
// relayout cure as B_M, proven R7->R9):
//   element (r,k): g=r>>4, c=k>>5, lane=((k&31)>>3)*16+(r&15), e=k&7
//   addr = BASE + (g*NCHUNK + c)*512 + lane*8 + e   (NCHUNK = Kdim/32)
constexpr int B_INPROJ = 0;        // 384x128 linear
constexpr int B_OUTW   = 49152;    // 128x128 (layout keep)
constexpr int B_LIN1   = 65536;    // 512x128, fragment order (NCHUNK=4)
constexpr int B_LIN2   = 131072;   // 128x512, fragment order (NCHUNK=16)
constexpr int B_OUTL   = 196608;   // 128x128, fragment order (NCHUNK=4)
constexpr int B_WKT    = 212992;   // 128x128
constexpr int B_KPW4   = 229376;   // 128 x float4 (fp32, 2048 B)
constexpr int B_M      = 230400;   // 128x1024 bf16, FRAGMENT-ORDER (see k_mkmat)
constexpr int B_OB2    = 361472;   // 128 fp32: out_b + outw@bv
constexpr size_t OFF_WB_BYTES  = 1587456;
constexpr size_t OFF_BIG_BYTES = 2310912;
constexpr size_t QK_BYTES = (size_t)NPTS * 1024 * 2;   // qkt rows; reused as z rows

typedef __attribute__((ext_vector_type(8))) short bfrag8;
typedef __attribute__((ext_vector_type(4))) float f32x4;

__device__ __forceinline__ float bf2f(unsigned short s) {
    return __uint_as_float(((unsigned)s) << 16);
}
__device__ __forceinline__ unsigned short f2bf(float f) {
    unsigned u = __float_as_uint(f);
    u += 0x7fffu + ((u >> 16) & 1u);
    return (unsigned short)(u >> 16);
}
__device__ __forceinline__ float ldE(const float* p, long i) { return p[i]; }
__device__ __forceinline__ float ldE(const unsigned short* p, long i) { return bf2f(p[i]); }
__device__ __forceinline__ void stE(float* p, long i, float v) { p[i] = v; }
__device__ __forceinline__ void stE(unsigned short* p, long i, float v) { p[i] = f2bf(v); }
__device__ __forceinline__ float ldF(const void* p, long i, int bf) {
    return bf ? bf2f(((const unsigned short*)p)[i]) : ((const float*)p)[i];
}
__device__ __forceinline__ bfrag8 ldfrag(const unsigned short* base, int stride, int lane, int k0) {
    return *(const bfrag8*)(base + (lane & 15) * stride + k0 + ((lane >> 4) << 3));
}
__device__ __forceinline__ unsigned cvtpk(float lo, float hi) {
    unsigned r;
    asm("v_cvt_pk_bf16_f32 %0, %1, %2" : "=v"(r) : "v"(lo), "v"(hi));
    return r;
}

// ---- dtype probe ----
__global__ __launch_bounds__(256) void k_detect(const unsigned short* __restrict__ f,
                                                int* __restrict__ flag) {
    __shared__ int cnt_s;
    if (threadIdx.x == 0) cnt_s = 0;
    __syncthreads();
    int sane = 0;
    for (int j = 0; j < 16; ++j) {
        unsigned short u = f[threadIdx.x * 16 + j];
        int e = (u >> 7) & 255;
        sane += (u == 0 || (e >= 100 && e <= 142)) ? 1 : 0;
    }
    atomicAdd(&cnt_s, sane);
    __syncthreads();
    if (threadIdx.x == 0) *flag = (cnt_s >= 3686) ? 1 : 0;
}

struct WTab {
    const void* src[20];
    int beg[20];
    int end[20];
    int bo[20];
};

__global__ __launch_bounds__(256) void k_cvt_weights(WTab tab, float* __restrict__ ws,
                                                     unsigned short* __restrict__ wsB,
                                                     const int* __restrict__ flagp) {
    int bf = *flagp;
    int gid = blockIdx.x * 256 + threadIdx.x;
    #pragma unroll
    for (int j = 0; j < 20; ++j) {
        if (gid >= tab.beg[j] && gid < tab.end[j]) {
            int off = gid - tab.beg[j];
            float v;
            unsigned short raw;
            if (bf) { raw = ((const unsigned short*)tab.src[j])[off]; v = bf2f(raw); }
            else    { v = ((const float*)tab.src[j])[off]; raw = f2bf(v); }
            ws[gid] = v;
            if (tab.bo[j] >= 0) wsB[tab.bo[j] + off] = raw;
            if (j == 0 && off >= 16384 && off < 32768) {
                int r = (off >> 7) - 128;
                int c = off & 127;
                wsB[B_WKT + c * C + r] = raw;
            }
            if (j == 6) {
                int c = off / 3, comp = off - 3 * c;
                ((float*)(wsB + B_KPW4))[c * 4 + comp] = v;
            }
            if (j == 7) {
                ((float*)(wsB + B_KPW4))[off * 4 + 3] = v;
            }
            // fragment-order stores (see layout comment at B_LIN1)
            if (j == 12) {   // lin1 [512][128]
                int r = off >> 7, k = off & 127;
                wsB[B_LIN1 + ((r >> 4) * 4 + (k >> 5)) * 512
                           + (((k & 31) >> 3) * 16 + (r & 15)) * 8 + (k & 7)] = raw;
            }
            if (j == 14) {   // lin2 [128][512]
                int r = off >> 9, k = off & 511;
                wsB[B_LIN2 + ((r >> 4) * 16 + (k >> 5)) * 512
                           + (((k & 31) >> 3) * 16 + (r & 15)) * 8 + (k & 7)] = raw;
            }
            if (j == 16) {   // outl [128][128]
                int r = off >> 7, k = off & 127;
                wsB[B_OUTL + ((r >> 4) * 4 + (k >> 5)) * 512
                           + (((k & 31) >> 3) * 16 + (r & 15)) * 8 + (k & 7)] = raw;
            }
        }
    }
}

// ---- precompute M in MFMA-fragment order ; ob2 ----
// M2 layout: for n-tile g=n>>4, k-chunk c=k>>5: element M[n][k] lives at
//   (g*32+c)*512 + lane*8 + (k&7),  lane = ((k&31)>>3)*16 + (n&15)
// so a wave's b-fragment load for (g,c) is ONE contiguous 1KB block.
__global__ __launch_bounds__(256) void k_mkmat(const float* __restrict__ wsW,
                                               unsigned short* __restrict__ wsBmut) {
    int j = blockIdx.x;   // output col n
    int t = threadIdx.x;
    const float* outw = wsW + OFF_OUT_W + j * C;
    #pragma unroll
    for (int i = 0; i < 4; ++i) {
        int idx = t + i * 256;        // k in 0..1023
        int h = idx >> 7, cp = idx & 127;
        float s = 0.f;
        const float* wvh = wsW + OFF_INPROJ_W + (256 + h * 16) * C + cp;
        const float* owh = outw + h * 16;
        #pragma unroll
        for (int d = 0; d < 16; ++d)
            s += owh[d] * wvh[d * C];
        int g = j >> 4, c = idx >> 5, r = idx & 31;
        int lane = ((r >> 3) << 4) + (j & 15);
        wsBmut[B_M + (g * 32 + c) * 512 + lane * 8 + (r & 7)] = f2bf(s);
    }
    if (t == 0) {
        float s = wsW[OFF_OUT_B + j];
        const float* bv = wsW + OFF_INPROJ_B + 256;
        for (int c = 0; c < C; ++c) s += outw[c] * bv[c];
        ((float*)(wsBmut + B_OB2))[j] = s;
    }
}

// ---- fused coords + qpos + Q projection + per-head qkt precompute ----
__global__ __launch_bounds__(256) void k_proj(
    const float* __restrict__ wsW, const unsigned short* __restrict__ wsB,
    const void* __restrict__ featv, const int* __restrict__ flagp,
    const int* __restrict__ indices, float* __restrict__ coords,
    unsigned short* __restrict__ Qk)
{
    __shared__ __align__(16) unsigned short sqb[32][136];
    __shared__ __align__(16) unsigned short sqh[32][136];
    __shared__ __align__(16) unsigned short sqk[2][32][136];
    __shared__ float scd[32][4];
    int t = threadIdx.x;
    int row0 = blockIdx.x * 32;
    const int bf = *flagp;
    if (t < 96) {
        int r = t / 3, j = t - 3 * r;
        int n = row0 + r;
        int srci = (j == 0) ? 3 : (j == 1 ? 2 : 1);
        float vs = (j == 2) ? 0.2f : 0.1f;
        float mn = (j == 2) ? -3.0f : -40.0f;
        float v = ((float)indices[n * 4 + srci] + 0.5f) * vs + mn;
        scd[r][j] = v;
        coords[n * 3 + j] = v;
    }
    __syncthreads();
    const float* qpw = wsW + OFF_QPOS_W;
    const float* qpb = wsW + OFF_QPOS_B;
    for (int i = t; i < 32 * C; i += 256) {
        int r = i >> 7, c = i & 127;
        float x = ldF(featv, (long)row0 * C + i, bf);
        float a = qpb[c] + scd[r][0]*qpw[c*3] + scd[r][1]*qpw[c*3+1] + scd[r][2]*qpw[c*3+2];
        sqb[r][c] = f2bf(x + fmaxf(a, 0.0f));
    }
    __syncthreads();
    int lane = t & 63, w = t >> 6;
    int col = lane & 15, quad = lane >> 4;
    for (int tid = w; tid < 16; tid += 4) {
        int mt = tid & 1, nt = tid >> 1, n0 = nt * 16;
        f32x4 acc = {0.f, 0.f, 0.f, 0.f};
        const unsigned short* aB = &sqb[mt*16][0];
        const unsigned short* bB = wsB + B_INPROJ + n0 * C;
        #pragma unroll
        for (int kt = 0; kt < 4; ++kt) {
            bfrag8 a = ldfrag(aB, 136, lane, kt*32);
            bfrag8 b = ldfrag(bB, C, lane, kt*32);
            acc = __builtin_amdgcn_mfma_f32_16x16x32_bf16(a, b, acc, 0, 0, 0);
        }
        #pragma unroll
        for (int r = 0; r < 4; ++r) {
            int n = n0 + col;
            sqh[mt*16 + quad*4 + r][n] = f2bf(acc[r] + wsW[OFF_INPROJ_B + n]);
        }
    }
    __syncthreads();
    const unsigned short* wkT = wsB + B_WKT;
    bfrag8 zf = {0,0,0,0,0,0,0,0};
    for (int h = 0; h < 8; ++h) {
        for (int tid = w; tid < 16; tid += 4) {
            int mt = tid & 1, nt = tid >> 1, n0 = nt * 16;
            bfrag8 a = zf, b = zf;
            if (quad < 2) {
                a = *(const bfrag8*)(&sqh[mt*16 + col][h*16 + quad*8]);
                b = *(const bfrag8*)(wkT + (n0 + col) * C + h*16 + quad*8);
            }
            f32x4 acc = {0.f, 0.f, 0.f, 0.f};
            acc = __builtin_amdgcn_mfma_f32_16x16x32_bf16(a, b, acc, 0, 0, 0);
            #pragma unroll
            for (int r = 0; r < 4; ++r)
                sqk[h & 1][mt*16 + quad*4 + r][n0 + col] = f2bf(acc[r]);
        }
        __syncthreads();
        for (int i = t; i < 2048; i += 256) {
            int r = i >> 6, cp = i & 63;
            unsigned v = *(const unsigned*)&sqk[h & 1][r][2 * cp];
            ((unsigned*)Qk)[(long)(row0 + r) * 512 + h * 64 + cp] = v;
        }
    }
}

// ---- attention: ONE wave per block + XCD swizzle (603us config, R20) ----
__global__ __launch_bounds__(64, 4) void k_attn(
    const float* __restrict__ wsW, const unsigned short* __restrict__ wsB,
    const float* __restrict__ coords, const int* __restrict__ key_idx,
    const void* __restrict__ featv, const int* __restrict__ flagp,
    unsigned short* __restrict__ Qk)
{
    __shared__ __align__(16) unsigned short P[32][136];
    __shared__ __align__(16) float SC[8][36];
    __shared__ __align__(16) float REL[32][4];
    __shared__ __align__(16) int   GS[32];

    int l = threadIdx.x;
    int bid = blockIdx.x;
    int n = (bid & 7) * (NPTS / 8) + (bid >> 3);   // bijective: 60000 % 8 == 0
    int col = l & 15, quad = l >> 4;
    int c0 = 2 * l;
    const int bf = *flagp;

    const float* kpwp = wsW + OFF_KPOS_W;
    float kw00 = kpwp[c0*3],   kw01 = kpwp[c0*3+1], kw02 = kpwp[c0*3+2];
    float kw10 = kpwp[c0*3+3], kw11 = kpwp[c0*3+4], kw12 = kpwp[c0*3+5];
    float kb0 = wsW[OFF_KPOS_B + c0], kb1 = wsW[OFF_KPOS_B + c0 + 1];

    if (l < 32) GS[l] = key_idx[n * K + l];
    float cenx = coords[n*3+0], ceny = coords[n*3+1], cenz = coords[n*3+2];
    bfrag8 ak[4];
    {
        const unsigned short* qkrow = Qk + (long)n * 1024 + (col & 7) * 128;
        #pragma unroll
        for (int ks = 0; ks < 4; ++ks)
            ak[ks] = *(const bfrag8*)(qkrow + ks * 32 + quad * 8);
    }
    if (l < 32) {
        int gc = max(GS[l], 0);
        REL[l][0] = coords[gc*3+0] - cenx;
        REL[l][1] = coords[gc*3+1] - ceny;
        REL[l][2] = coords[gc*3+2] - cenz;
        REL[l][3] = 0.f;
    }
    __syncthreads();

    if (bf) {
        const unsigned* xb = (const unsigned*)featv;
        unsigned xv[32];
        #pragma unroll
        for (int k = 0; k < K; ++k) {
            int gcs = __builtin_amdgcn_readfirstlane(max(GS[k], 0));
            xv[k] = xb[(long)gcs * 64 + l];
        }
        #pragma unroll
        for (int k = 0; k < K; ++k) {
            float4 rr = *(const float4*)&REL[k][0];
            float p0 = bf2f((unsigned short)xv[k])
                     + fmaxf(kb0 + rr.x*kw00 + rr.y*kw01 + rr.z*kw02, 0.f);
            float p1 = bf2f((unsigned short)(xv[k] >> 16))
                     + fmaxf(kb1 + rr.x*kw10 + rr.y*kw11 + rr.z*kw12, 0.f);
            *(unsigned*)&P[k][c0] = cvtpk(p0, p1);
        }
    } else {
        const float2* xf = (const float2*)featv;
        #pragma unroll
        for (int kc = 0; kc < K; kc += 16) {
            float2 xv[16];
            #pragma unroll
            for (int j = 0; j < 16; ++j) {
                int gcs = __builtin_amdgcn_readfirstlane(max(GS[kc + j], 0));
                xv[j] = xf[(long)gcs * 64 + l];
            }
            #pragma unroll
            for (int j = 0; j < 16; ++j) {
                int k = kc + j;
                float4 rr = *(const float4*)&REL[k][0];
                float p0 = xv[j].x + fmaxf(kb0 + rr.x*kw00 + rr.y*kw01 + rr.z*kw02, 0.f);
                float p1 = xv[j].y + fmaxf(kb1 + rr.x*kw10 + rr.y*kw11 + rr.z*kw12, 0.f);
                *(unsigned*)&P[k][c0] = cvtpk(p0, p1);
            }
        }
    }
    __syncthreads();

    #pragma unroll
    for (int nt = 0; nt < 2; ++nt) {
        int g = GS[nt * 16 + col];
        f32x4 acc = {0.f, 0.f, 0.f, 0.f};
        #pragma unroll
        for (int ks = 0; ks < 4; ++ks) {
            bfrag8 bp = *(const bfrag8*)(&P[nt * 16 + col][0] + ks * 32 + quad * 8);
            acc = __builtin_amdgcn_mfma_f32_16x16x32_bf16(ak[ks], bp, acc, 0, 0, 0);
        }
        if (quad < 2) {
            #pragma unroll
            for (int r = 0; r < 4; ++r) {
                int h = quad * 4 + r, k = nt * 16 + col;
                SC[h][k] = (g < 0) ? -1e30f : acc[r] * 0.25f;
            }
        }
    }
    __syncthreads();

    {
        int h = l >> 3, sub = l & 7;
        float v0 = SC[h][sub],      v1 = SC[h][sub + 8];
        float v2 = SC[h][sub + 16], v3 = SC[h][sub + 24];
        float m = fmaxf(fmaxf(v0, v1), fmaxf(v2, v3));
        m = fmaxf(m, __shfl_xor(m, 1));
        m = fmaxf(m, __shfl_xor(m, 2));
        m = fmaxf(m, __shfl_xor(m, 4));
        float e0 = __expf(v0 - m), e1 = __expf(v1 - m), e2 = __expf(v2 - m), e3 = __expf(v3 - m);
        float s = e0 + e1 + e2 + e3;
        s += __shfl_xor(s, 1);
        s += __shfl_xor(s, 2);
        s += __shfl_xor(s, 4);
        float inv = 1.0f / s;
        SC[h][sub]      = e0 * inv;
        SC[h][sub + 8]  = e1 * inv;
        SC[h][sub + 16] = e2 * inv;
        SC[h][sub + 24] = e3 * inv;
    }
    __syncthreads();

    {
        union { bfrag8 f; unsigned u32v[4]; } at8;
        #pragma unroll
        for (int j = 0; j < 4; ++j) {
            float a0 = SC[col & 7][quad * 8 + 2*j];
            float a1 = SC[col & 7][quad * 8 + 2*j + 1];
            at8.u32v[j] = cvtpk(a0, a1);
        }
        #pragma unroll
        for (int nt = 0; nt < 8; ++nt) {
            union { bfrag8 f; unsigned short u[8]; } bt;
            #pragma unroll
            for (int j = 0; j < 8; ++j)
                bt.u[j] = P[quad * 8 + j][nt * 16 + col];
            f32x4 d = {0.f, 0.f, 0.f, 0.f};
            d = __builtin_amdgcn_mfma_f32_16x16x32_bf16(at8.f, bt.f, d, 0, 0, 0);
            // z output aliased into P rows 0..7 of this (now dead) column stripe
            if (quad < 2) {
                #pragma unroll
                for (int r = 0; r < 4; ++r)
                    P[quad * 4 + r][nt * 16 + col] = f2bf(d[r]);
            }
        }
    }
    __syncthreads();

    {
        unsigned* zout = (unsigned*)(Qk + (long)n * 1024);
        #pragma unroll
        for (int j = 0; j < 8; ++j) {
            int idx = l + j * 64;
            zout[idx] = *(const unsigned*)&P[idx >> 6][(idx & 63) * 2];
        }
    }
}

// ---- out-proj from z: y1 = feat + z @ M^T + ob2 ; bn1 stats ----
template <typename T>
__global__ __launch_bounds__(256) void k_outproj(
    const float* __restrict__ wsW, const unsigned short* __restrict__ wsB,
    const void* __restrict__ featv, const int* __restrict__ flagp,
    const unsigned short* __restrict__ Z, T* __restrict__ Y, float* __restrict__ acc_s)
{
    __shared__ float syf[32][132];
    int t = threadIdx.x;
    int row0 = blockIdx.x * 32;
    const int bf = *flagp;
    int lane = t & 63, w = t >> 6;
    int col = lane & 15, quad = lane >> 4;
    const float* ob2 = (const float*)(wsB + B_OB2);
    int mt = w & 1, ntb = w >> 1;
    f32x4 acc[4] = {{0,0,0,0},{0,0,0,0},{0,0,0,0},{0,0,0,0}};
    const unsigned short* zrow = Z + (long)(row0 + mt*16 + col) * 1024 + quad * 8;
    const unsigned short* mbase = wsB + B_M + lane * 8;
    #pragma unroll
    for (int ktc = 0; ktc < 4; ++ktc) {
        bfrag8 a[8];
        #pragma unroll
        for (int j = 0; j < 8; ++j)
            a[j] = *(const bfrag8*)(zrow + (ktc * 8 + j) * 32);
        __builtin_amdgcn_sched_barrier(0);
        bfrag8 bA[8], bB[8];
#define LOADB(dst, ii) { const unsigned short* mb = mbase + ((ntb + 2*(ii))*32 + ktc*8)*512; \
    _Pragma("unroll") for (int j = 0; j < 8; ++j) dst[j] = *(const bfrag8*)(mb + j*512); }
#define MFMA8(buf, ii) { _Pragma("unroll") for (int j = 0; j < 8; ++j) \
    acc[ii] = __builtin_amdgcn_mfma_f32_16x16x32_bf16(a[j], buf[j], acc[ii], 0, 0, 0); }
        LOADB(bA, 0)
        __builtin_amdgcn_sched_barrier(0);
        LOADB(bB, 1)
        __builtin_amdgcn_sched_barrier(0);
        MFMA8(bA, 0)
        LOADB(bA, 2)
        __builtin_amdgcn_sched_barrier(0);
        MFMA8(bB, 1)
        LOADB(bB, 3)
        __builtin_amdgcn_sched_barrier(0);
        MFMA8(bA, 2)
        MFMA8(bB, 3)
#undef LOADB
#undef MFMA8
    }
    #pragma unroll
    for (int i = 0; i < 4; ++i) {
        int n0 = (ntb + 2 * i) * 16;
        #pragma unroll
        for (int r = 0; r < 4; ++r) {
            int m = mt*16 + quad*4 + r;
            int n = n0 + col;
            syf[m][n] = acc[i][r] + ob2[n] + ldF(featv, (long)(row0+m)*C + n, bf);
        }
    }
    __syncthreads();
    for (int i = t; i < 32 * C; i += 256)
        stE(Y, (long)row0 * C + i, syf[i>>7][i&127]);
    if (t < C) {
        float s = 0.f, sq = 0.f;
        for (int r = 0; r < 32; ++r) { float v = syf[r][t]; s += v; sq += v*v; }
        atomicAdd(&acc_s[t], s);
        atomicAdd(&acc_s[C + t], sq);
    }
}

// ---- bn1 + FFN + residual + bn2 stats ----
// LIN1/LIN2 in fragment order: each wave b-load is ONE contiguous 1KB block
// (R20: scattered b-loads left k_ffn latency-serialized at 4% MfmaUtil).
template <typename T>
__global__ __launch_bounds__(256) void k_ffn(
    const float* __restrict__ wsW, const unsigned short* __restrict__ wsB,
    T* __restrict__ Y, const float* __restrict__ acc1, float* __restrict__ acc2)
{
    __shared__ __align__(16) unsigned short sxb[32][136];
    __shared__ __align__(16) unsigned short sh[32][264];   // one FF half
    __shared__ float nsc[C], nsh[C];
    float (*syf)[132] = (float(*)[132])sh;                 // aliased after last half
    int t = threadIdx.x;
    int row0 = blockIdx.x * 32;
    if (t < C) {
        float m = acc1[t] * (1.0f/NPTS);
        float v = acc1[C+t] * (1.0f/NPTS) - m*m;
        float rs = rsqrtf(v + EPS);
        float sc = rs * wsW[OFF_N1G + t];
        nsc[t] = sc;
        nsh[t] = wsW[OFF_N1B + t] - m * sc;
    }
    __syncthreads();
    for (int i = t; i < 32 * C; i += 256) {
        int c = i & 127;
        sxb[i>>7][c] = f2bf(ldE(Y, (long)row0 * C + i) * nsc[c] + nsh[c]);
    }
    __syncthreads();
    int lane = t & 63, w = t >> 6;
    int col = lane & 15, quad = lane >> 4;
    int mtw = w & 1, ntb = w >> 1;
    f32x4 accT[4] = {{0,0,0,0},{0,0,0,0},{0,0,0,0},{0,0,0,0}};
    #pragma unroll
    for (int half = 0; half < 2; ++half) {
        // GEMM1: 32 x [C] @ lin1[half*256 .. +256]^T -> sh (relu, bf16)
        for (int tid = w; tid < 32; tid += 4) {
            int mt = tid & 1, nt = tid >> 1, n0 = nt * 16;
            f32x4 acc = {0.f, 0.f, 0.f, 0.f};
            const unsigned short* aB = &sxb[mt*16][0];
            // fragment order: row-tile g = half*16 + nt, chunk c = kt
            const unsigned short* bB = wsB + B_LIN1 + (half*16 + nt) * 4 * 512 + lane * 8;
            bfrag8 bv4[4];
            #pragma unroll
            for (int kt = 0; kt < 4; ++kt)
                bv4[kt] = *(const bfrag8*)(bB + kt * 512);
            __builtin_amdgcn_sched_barrier(0);
            #pragma unroll
            for (int kt = 0; kt < 4; ++kt) {
                bfrag8 a = ldfrag(aB, 136, lane, kt*32);
                acc = __builtin_amdgcn_mfma_f32_16x16x32_bf16(a, bv4[kt], acc, 0, 0, 0);
            }
            #pragma unroll
            for (int r = 0; r < 4; ++r) {
                int m = mt*16 + quad*4 + r;
                int nf = half * 256 + n0 + col;
                sh[m][n0 + col] = f2bf(fmaxf(acc[r] + wsW[OFF_LIN1_B + nf], 0.f));
            }
        }
        __syncthreads();
        // GEMM2 partial-K accumulate over this half (fragment-order b, pinned)
        #pragma unroll
        for (int i = 0; i < 4; ++i) {
            int mt = mtw, n0 = (ntb + 2 * i) * 16;
            const unsigned short* aB = &sh[mt*16][0];
            // fragment order: row-tile g = ntb+2i, chunk c = half*8 + kt
            const unsigned short* bB = wsB + B_LIN2 + ((ntb + 2*i) * 16 + half * 8) * 512 + lane * 8;
            bfrag8 b[8];
            #pragma unroll
            for (int kt = 0; kt < 8; ++kt)
                b[kt] = *(const bfrag8*)(bB + kt * 512);
            __builtin_amdgcn_sched_barrier(0);
            #pragma unroll
            for (int kt = 0; kt < 8; ++kt) {
                bfrag8 a = ldfrag(aB, 264, lane, kt*32);
                accT[i] = __builtin_amdgcn_mfma_f32_16x16x32_bf16(a, b[kt], accT[i], 0, 0, 0);
            }
        }
        __syncthreads();
    }
    #pragma unroll
    for (int i = 0; i < 4; ++i) {
        int n0 = (ntb + 2 * i) * 16;
        #pragma unroll
        for (int r = 0; r < 4; ++r) {
            int m = mtw*16 + quad*4 + r;
            int n = n0 + col;
            syf[m][n] = accT[i][r] + wsW[OFF_LIN2_B + n] + bf2f(sxb[m][n]);
        }
    }
    __syncthreads();
    for (int i = t; i < 32 * C; i += 256)
        stE(Y, (long)row0 * C + i, syf[i>>7][i&127]);
    if (t < C) {
        float s = 0.f, sq = 0.f;
        for (int r = 0; r < 32; ++r) { float v = syf[r][t]; s += v; sq += v*v; }
        atomicAdd(&acc2[t], s);
        atomicAdd(&acc2[C+t], sq);
    }
}

// ---- bn2 + output linear + bn3 stats (fragment-order OUTL) ----
template <typename T>
__global__ __launch_bounds__(256) void k_outl(
    const float* __restrict__ wsW, const unsigned short* __restrict__ wsB,
    T* __restrict__ Y, const float* __restrict__ acc2, float* __restrict__ acc3)
{
    __shared__ __align__(16) unsigned short sxb[32][136];
    __shared__ float syf[32][132];
    __shared__ float nsc[C], nsh[C];
    int t = threadIdx.x;
    int row0 = blockIdx.x * 32;
    if (t < C) {
        float m = acc2[t] * (1.0f/NPTS);
        float v = acc2[C+t] * (1.0f/NPTS) - m*m;
        float rs = rsqrtf(v + EPS);
        float sc = rs * wsW[OFF_N2G + t];
        nsc[t] = sc;
        nsh[t] = wsW[OFF_N2B + t] - m * sc;
    }
    __syncthreads();
    for (int i = t; i < 32 * C; i += 256) {
        int c = i & 127;
        sxb[i>>7][c] = f2bf(ldE(Y, (long)row0 * C + i) * nsc[c] + nsh[c]);
    }
    __syncthreads();
    int lane = t & 63, w = t >> 6;
    int col = lane & 15, quad = lane >> 4;
    for (int tid = w; tid < 16; tid += 4) {
        int mt = tid & 1, nt = tid >> 1, n0 = nt * 16;
        f32x4 acc = {0.f, 0.f, 0.f, 0.f};
        const unsigned short* aB = &sxb[mt*16][0];
        // fragment order: row-tile g = nt, chunk c = kt
        const unsigned short* bB = wsB + B_OUTL + nt * 4 * 512 + lane * 8;
        bfrag8 bv4[4];
        #pragma unroll
        for (int kt = 0; kt < 4; ++kt)
            bv4[kt] = *(const bfrag8*)(bB + kt * 512);
        __builtin_amdgcn_sched_barrier(0);
        #pragma unroll
        for (int kt = 0; kt < 4; ++kt) {
            bfrag8 a = ldfrag(aB, 136, lane, kt*32);
            acc = __builtin_amdgcn_mfma_f32_16x16x32_bf16(a, bv4[kt], acc, 0, 0, 0);
        }
        #pragma unroll
        for (int r = 0; r < 4; ++r) {
            int m = mt*16 + quad*4 + r;
            int n = n0 + col;
            syf[m][n] = acc[r] + wsW[OFF_OUTL_B + n];
        }
    }
    __syncthreads();
    for (int i = t; i < 32 * CO; i += 256)
        stE(Y, (long)row0 * CO + i, syf[i>>7][i&127]);
    if (t < CO) {
        float s = 0.f, sq = 0.f;
        for (int r = 0; r < 32; ++r) { float v = syf[r][t]; s += v; sq += v*v; }
        atomicAdd(&acc3[t], s);
        atomicAdd(&acc3[CO+t], sq);
    }
}

// ---- final BN + relu -> output ----
template <typename T>
__global__ __launch_bounds__(256) void k_final(
    const float* __restrict__ wsW, const T* __restrict__ Y,
    const float* __restrict__ acc3, const int* __restrict__ flagp,
    void* __restrict__ out)
{
    long i = (long)blockIdx.x * 256 + threadIdx.x;
    int c = (int)(i & (CO-1));
    float m = acc3[c] * (1.0f/NPTS);
    float v = acc3[CO+c] * (1.0f/NPTS) - m*m;
    float rs = rsqrtf(v + EPS);
    float y = (ldE(Y, i) - m) * rs * wsW[OFF_BOG + c] + wsW[OFF_BOB + c];
    y = fmaxf(y, 0.f);
    if (*flagp) ((unsigned short*)out)[i] = f2bf(y);
    else        ((float*)out)[i] = y;
}

extern "C" void kernel_launch(void* const* d_in, const int* in_sizes, int n_in,
                              void* d_out, int out_size, void* d_ws, size_t ws_size,
                              hipStream_t stream)
{
    char* base = (char*)d_ws;
    float* wsW = (float*)base;
    float* acc1 = wsW + WTOTAL;
    float* acc2 = acc1 + 256;
    float* acc3 = acc2 + 256;
    int* flagp = (int*)(wsW + WTOTAL + 768);
    float* coords = wsW + WTOTAL + 776;
    unsigned short* wsB = (unsigned short*)(base + OFF_WB_BYTES);

    const void* featv = d_in[0];
    const int* indices = (const int*)d_in[1];
    const int* key_idx = (const int*)d_in[2];

    hipMemsetAsync(acc1, 0, 768 * sizeof(float), stream);
    k_detect<<<1, 256, 0, stream>>>((const unsigned short*)d_in[0], flagp);

    // LIN1 / LIN2 / OUTL go through fragment-order special cases (bo = -1)
    static const int cnt[20] = {49152,384,16384,128,384,128,384,128,128,128,
                                128,128,65536,512,65536,128,16384,128,128,128};
    static const int bofs[20] = {B_INPROJ,-1,B_OUTW,-1,-1,-1,-1,-1,-1,-1,
                                 -1,-1,-1,-1,-1,-1,-1,-1,-1,-1};
    WTab tab;
    int off = 0;
    for (int j = 0; j < 20; ++j) {
        tab.src[j] = d_in[3 + j];
        tab.beg[j] = off;
        tab.end[j] = off + cnt[j];
        tab.bo[j] = bofs[j];
        off += cnt[j];
    }
    k_cvt_weights<<<WTOTAL/256, 256, 0, stream>>>(tab, wsW, wsB, flagp);
    k_mkmat<<<128, 256, 0, stream>>>(wsW, wsB);

    size_t bigN = (size_t)NPTS * C;
    bool f32mode = (ws_size >= OFF_BIG_BYTES + QK_BYTES + bigN * 4);

    unsigned short* Qk = (unsigned short*)(base + OFF_BIG_BYTES);

    k_proj<<<NPTS/32, 256, 0, stream>>>(wsW, wsB, featv, flagp, indices, coords, Qk);
    k_attn<<<NPTS, 64, 0, stream>>>(wsW, wsB, coords, key_idx, featv, flagp, Qk);

    if (f32mode) {
        float* Y = (float*)(base + OFF_BIG_BYTES + QK_BYTES);
        k_outproj<float><<<NPTS/32, 256, 0, stream>>>(wsW, wsB, featv, flagp, Qk, Y, acc1);
        k_ffn<float><<<NPTS/32, 256, 0, stream>>>(wsW, wsB, Y, acc1, acc2);
        k_outl<float><<<NPTS/32, 256, 0, stream>>>(wsW, wsB, Y, acc2, acc3);
        k_final<float><<<(NPTS*CO)/256, 256, 0, stream>>>(wsW, Y, acc3, flagp, d_out);
    } else {
        unsigned short* Y = (unsigned short*)(base + OFF_BIG_BYTES + QK_BYTES);
        k_outproj<unsigned short><<<NPTS/32, 256, 0, stream>>>(wsW, wsB, featv, flagp, Qk, Y, acc1);
        k_ffn<unsigned short><<<NPTS/32, 256, 0, stream>>>(wsW, wsB, Y, acc1, acc2);
        k_outl<unsigned short><<<NPTS/32, 256, 0, stream>>>(wsW, wsB, Y, acc2, acc3);
        k_final<unsigned short><<<(NPTS*CO)/256, 256, 0, stream>>>(wsW, Y, acc3, flagp, d_out);
    }
}